// Round 11
// baseline (581.486 us; speedup 1.0000x reference)
//
#include <hip/hip_runtime.h>
#include <stdint.h>

typedef __bf16 bf16_t;
typedef bf16_t bf16x8 __attribute__((ext_vector_type(8)));
typedef float floatx4 __attribute__((ext_vector_type(4)));

__device__ __forceinline__ unsigned short f2bf(float f) {
  union { float f; uint32_t u; } v; v.f = f;
  return (unsigned short)((v.u + 0x7fffu + ((v.u >> 16) & 1u)) >> 16);
}

#define GLD16(g, l)                                                            \
  __builtin_amdgcn_global_load_lds(                                            \
      (const __attribute__((address_space(1))) void*)(g),                      \
      (__attribute__((address_space(3))) void*)(l), 16, 0, 0)

// ---------------------------------------------------------------------------
// 256x256 double-buffered 2-phase GEMM — now the ONLY GEMM kernel.
// Round-11: + split-K A-offset (sA) and fp32-partial output (OUT_BF16=false)
// so o-proj and ffn2 (N=512 shapes) can use it with z=4 split-K:
// grid dim3(2,32,4) = 256 blocks = 1 block/CU (128 KB LDS), 16/8 K-steps.
// Structure unchanged from the round-10 verified version: 512 thr = 8 waves
// (2x4), wave tile 128x64, acc[8][4], STAGE(t+1) issued before compute,
// ONE barrier per K-step (drains next tile's DMA + fences buf reads).
// ---------------------------------------------------------------------------
template <int BIAS_MODE, bool RELU, bool OUT_BF16>
__global__ __launch_bounds__(512, 2) void gemm_bt2(
    const unsigned short* __restrict__ A, const unsigned short* __restrict__ Bt,
    void* __restrict__ C, const float* __restrict__ bias, int K, int lda,
    int ldb, int ldc, long sA, long sB, long sC) {
  __shared__ unsigned short As[2][256 * 64];
  __shared__ unsigned short Bs[2][256 * 64];
  const int tid = threadIdx.x;
  const int lane = tid & 63;
  const int wave = tid >> 6;        // 0..7
  const unsigned short* Ab = A + blockIdx.z * sA + (long)blockIdx.y * 256 * lda;
  const unsigned short* Bb = Bt + blockIdx.z * sB + (long)blockIdx.x * 256 * ldb;
  const int wm = (wave & 1) << 7;   // 0/128
  const int wn = (wave >> 1) << 6;  // 0/64/128/192

  floatx4 acc[8][4] = {};

  const int sr = tid >> 3;  // staging row 0..63 (+64 per issue)
  const int sc = tid & 7;   // staging chunk 0..7

  // stage K-tile starting at kt into buffer bf (wave-linear LDS dest,
  // chunk-XOR pre-swizzled global source — both-sides rule)
  auto STAGE = [&](int kt, int bf) {
#pragma unroll
    for (int i = 0; i < 4; ++i) {
      int r = sr + i * 64;
      int gc = sc ^ (r & 7);
      GLD16(Ab + (long)r * lda + kt + gc * 8,
            As[bf] + (i * 512 + wave * 64) * 8);
    }
#pragma unroll
    for (int i = 0; i < 4; ++i) {
      int r = sr + i * 64;
      int gc = sc ^ (r & 7);
      GLD16(Bb + (long)r * ldb + kt + gc * 8,
            Bs[bf] + (i * 512 + wave * 64) * 8);
    }
  };

  STAGE(0, 0);
  __syncthreads();  // drains tile-0 DMA

  const int nt = K >> 6;
  for (int t = 0; t < nt; ++t) {
    // issue next tile's DMA FIRST; it flies under this tile's compute and
    // drains at this step's single end barrier. The destination buffer's
    // last reads completed at the (t-1) end barrier.
    if (t + 1 < nt) STAGE((t + 1) << 6, (t + 1) & 1);
    const unsigned short* Al = As[t & 1];
    const unsigned short* Bl = Bs[t & 1];
#pragma unroll
    for (int ks = 0; ks < 2; ++ks) {
      bf16x8 af[8], bfr[4];
#pragma unroll
      for (int i = 0; i < 8; ++i) {
        int row = wm + i * 16 + (lane & 15);
        int ch = (ks * 4 + (lane >> 4)) ^ (row & 7);
        af[i] = *(const bf16x8*)(Al + row * 64 + ch * 8);
      }
#pragma unroll
      for (int j = 0; j < 4; ++j) {
        int row = wn + j * 16 + (lane & 15);
        int ch = (ks * 4 + (lane >> 4)) ^ (row & 7);
        bfr[j] = *(const bf16x8*)(Bl + row * 64 + ch * 8);
      }
#pragma unroll
      for (int i = 0; i < 8; ++i)
#pragma unroll
        for (int j = 0; j < 4; ++j)
          acc[i][j] = __builtin_amdgcn_mfma_f32_16x16x32_bf16(af[i], bfr[j],
                                                              acc[i][j], 0, 0, 0);
    }
    __syncthreads();  // drains STAGE(t+1) DMA; all reads of buf[t&1] done
  }

  const int rl = (lane >> 4) << 2;
  const int cl = lane & 15;
#pragma unroll
  for (int i = 0; i < 8; ++i) {
#pragma unroll
    for (int j = 0; j < 4; ++j) {
#pragma unroll
      for (int rg = 0; rg < 4; ++rg) {
        int row = (blockIdx.y << 8) + wm + i * 16 + rl + rg;
        int col = (blockIdx.x << 8) + wn + j * 16 + cl;
        float v = acc[i][j][rg];
        if (BIAS_MODE == 1) v += bias[col];
        if (BIAS_MODE == 2) v += bias[row];
        if (RELU) v = fmaxf(v, 0.0f);
        long idx = blockIdx.z * sC + (long)row * ldc + col;
        if (OUT_BF16)
          ((unsigned short*)C)[idx] = f2bf(v);
        else
          ((float*)C)[idx] = v;
      }
    }
  }
}

// ---------------------------------------------------------------------------
// Flash attention — round-9 version, FROZEN (103.7 µs, conflicts 2.1e6).
// Round-0 pipeline + isolated 4-bit K swizzle (verified win).
// ---------------------------------------------------------------------------
__global__ __launch_bounds__(512, 2) void attn(
    const unsigned short* __restrict__ qk, const unsigned short* __restrict__ vt,
    unsigned short* __restrict__ ctx) {
  __shared__ unsigned short ldsK[2][32 * 512];  // 64 KB, chunk-swizzled rows
  __shared__ unsigned short ldsV[2][32 * 512];  // 64 KB, bank-swizzled slots
  __shared__ unsigned short ldsP[128 * 40];     // 10 KB, pad-40 rows
  __shared__ float ldsL[128];                   // per-row l (final)

  const int tid = threadIdx.x;
  const int lane = tid & 63;
  const int wave = tid >> 6;  // 0..7
  const int quad = lane >> 4;
  const int l15 = lane & 15;
  const int b = blockIdx.x >> 3;  // group-local batch 0..3
  const int h = blockIdx.x & 7;
  const int qblk = blockIdx.y << 7;  // 128-row block base within batch
  const float cs = 0.044194173824159216f * 1.4426950408889634f;  // scale*log2e

  // Q fragments for this wave's 16 S-rows (qblk + wave*16 + l15)
  bf16x8 qf[16];
  {
    const unsigned short* qp =
        qk + (long)(b * 1024 + qblk + wave * 16 + l15) * 8192 + h * 512 +
        (quad << 3);
#pragma unroll
    for (int ks = 0; ks < 16; ++ks) qf[ks] = *(const bf16x8*)(qp + ks * 32);
  }

  floatx4 o[32];  // o[qb*4+db]: rows qb*16+quad*4+reg, cols wave*64+db*16+l15
#pragma unroll
  for (int i = 0; i < 32; ++i) o[i] = floatx4{0.f, 0.f, 0.f, 0.f};
  floatx4 l_i = floatx4{0.f, 0.f, 0.f, 0.f};  // per-lane partial row sums

  // V staging source mapping (lane -> slot lane): d-local = lane>>2,
  // kc = ((lane&3) - (lane>>3)) & 3  (inverse of the read swizzle)
  const int st_d = lane >> 2;
  const int st_kc = ((lane & 3) - (lane >> 3)) & 3;

  // prologue: stage K[0] and V[0]
  {
#pragma unroll
    for (int i = 0; i < 4; ++i) {
      int r = i * 8 + wave;
      int gc = (lane & ~15) | ((lane ^ r) & 15);
      GLD16(qk + (long)(b * 1024 + r) * 8192 + 4096 + h * 512 + gc * 8,
            ldsK[0] + r * 512);
    }
#pragma unroll
    for (int i = 0; i < 4; ++i) {
      int j = i * 8 + wave;
      GLD16(vt + (long)(b * 4096 + h * 512 + j * 16 + st_d) * 1024 + st_kc * 8,
            ldsV[0] + j * 512);
    }
  }
  __syncthreads();  // drains K[0]+V[0] DMA

  for (int kt = 0; kt < 32; ++kt) {
    const unsigned short* kb = ldsK[kt & 1];
    const unsigned short* vb = ldsV[kt & 1];
    // prefetch K[kt+1] and V[kt+1]; drained at this iteration's END barrier
    if (kt + 1 < 32) {
#pragma unroll
      for (int i = 0; i < 4; ++i) {
        int r = i * 8 + wave;
        int gc = (lane & ~15) | ((lane ^ r) & 15);
        GLD16(qk + (long)(b * 1024 + (kt + 1) * 32 + r) * 8192 + 4096 +
                  h * 512 + gc * 8,
              ldsK[(kt + 1) & 1] + r * 512);
      }
#pragma unroll
      for (int i = 0; i < 4; ++i) {
        int j = i * 8 + wave;
        GLD16(vt + (long)(b * 4096 + h * 512 + j * 16 + st_d) * 1024 +
                  (kt + 1) * 32 + st_kc * 8,
              ldsV[(kt + 1) & 1] + j * 512);
      }
    }

    // --- S = Q K^T : this wave's 16 rows x 32 keys (reads kb) ---
    floatx4 s0 = floatx4{0.f, 0.f, 0.f, 0.f}, s1 = floatx4{0.f, 0.f, 0.f, 0.f};
#pragma unroll
    for (int ks = 0; ks < 16; ++ks) {
      int ch = ks * 4 + quad;
      int sw = (ch & ~15) | ((ch ^ l15) & 15);
      bf16x8 k0 = *(const bf16x8*)(kb + l15 * 512 + sw * 8);
      bf16x8 k1 = *(const bf16x8*)(kb + (16 + l15) * 512 + sw * 8);
      s0 = __builtin_amdgcn_mfma_f32_16x16x32_bf16(qf[ks], k0, s0, 0, 0, 0);
      s1 = __builtin_amdgcn_mfma_f32_16x16x32_bf16(qf[ks], k1, s1, 0, 0, 0);
    }

    // --- no-max softmax: p = 2^(s*scale*log2e); accumulate per-lane l ---
    {
      unsigned short* pw = ldsP + wave * 16 * 40;
      const int rb = quad << 2;
#pragma unroll
      for (int r = 0; r < 4; ++r) {
        float e0 = __builtin_amdgcn_exp2f(s0[r] * cs);
        float e1 = __builtin_amdgcn_exp2f(s1[r] * cs);
        l_i[r] += e0 + e1;
        pw[(rb + r) * 40 + l15] = f2bf(e0);
        pw[(rb + r) * 40 + 16 + l15] = f2bf(e1);
      }
    }
    // mid-barrier: LDS-only visibility (P); K/V[kt+1] DMAs stay in flight.
    asm volatile("s_waitcnt lgkmcnt(0)\n\ts_barrier" ::: "memory");

    // --- O += P @ V (d-split: this wave's 64 dims) ---
#pragma unroll
    for (int half = 0; half < 2; ++half) {
      bf16x8 pf[4];
#pragma unroll
      for (int q4 = 0; q4 < 4; ++q4)
        pf[q4] = *(const bf16x8*)(ldsP + ((half * 4 + q4) * 16 + l15) * 40 +
                                  (quad << 3));
#pragma unroll
      for (int db = 0; db < 4; ++db) {
        int n = wave * 4 + db;
        bf16x8 vf = *(const bf16x8*)(
            vb + n * 512 + (l15 * 4 + ((quad + (l15 >> 1)) & 3)) * 8);
#pragma unroll
        for (int q4 = 0; q4 < 4; ++q4)
          o[(half * 4 + q4) * 4 + db] = __builtin_amdgcn_mfma_f32_16x16x32_bf16(
              pf[q4], vf, o[(half * 4 + q4) * 4 + db], 0, 0, 0);
      }
    }
    __syncthreads();  // drains K/V[kt+1] DMA; all LDS reads of kt done
  }

  // final l reduction across the 16 lanes holding each row's partials
#pragma unroll
  for (int r = 0; r < 4; ++r) {
    float rs = l_i[r];
    rs += __shfl_xor(rs, 1);
    rs += __shfl_xor(rs, 2);
    rs += __shfl_xor(rs, 4);
    rs += __shfl_xor(rs, 8);
    if (l15 == 0) ldsL[wave * 16 + (quad << 2) + r] = rs;
  }
  __syncthreads();

#pragma unroll
  for (int qb = 0; qb < 8; ++qb) {
    floatx4 lv = *(const floatx4*)(ldsL + qb * 16 + (quad << 2));
    floatx4 inv;
#pragma unroll
    for (int r = 0; r < 4; ++r) inv[r] = 1.0f / lv[r];
#pragma unroll
    for (int db = 0; db < 4; ++db) {
#pragma unroll
      for (int r = 0; r < 4; ++r) {
        long row = (long)(b * 1024 + qblk + qb * 16 + (quad << 2) + r);
        ctx[row * 4096 + h * 512 + wave * 64 + db * 16 + l15] =
            f2bf(o[qb * 4 + db][r] * inv[r]);
      }
    }
  }
}

// ---------------------------------------------------------------------------
// Fused split-K reduce + bias + residual + LayerNorm over last dim (512).
// float4-vectorized, 2 rows per 256-thread block.
// ---------------------------------------------------------------------------
template <int NP, bool WB>
__global__ __launch_bounds__(256) void ln_reduce(
    const float* __restrict__ p, long sP, const float* __restrict__ bias,
    const float* __restrict__ resid, const float* __restrict__ gamma,
    const float* __restrict__ beta, float* __restrict__ of,
    unsigned short* __restrict__ ob) {
  const int rloc = threadIdx.x >> 7;              // 0..1: row within block
  const long row = (long)blockIdx.x * 2 + rloc;
  const int t = threadIdx.x & 127;                // 0..127: col/4 within row
  float4 a = ((const float4*)(p + row * 512))[t];
#pragma unroll
  for (int i = 1; i < NP; ++i) {
    const float4 ai = ((const float4*)(p + i * sP + row * 512))[t];
    a.x += ai.x;
    a.y += ai.y;
    a.z += ai.z;
    a.w += ai.w;
  }
  const float4 rv = ((const float4*)(resid + row * 512))[t];
  const float4 bv = ((const float4*)bias)[t];
  const float x0 = a.x + bv.x + rv.x;
  const float x1 = a.y + bv.y + rv.y;
  const float x2 = a.z + bv.z + rv.z;
  const float x3 = a.w + bv.w + rv.w;
  float s = x0 + x1 + x2 + x3;
  float ss = x0 * x0 + x1 * x1 + x2 * x2 + x3 * x3;
#pragma unroll
  for (int d = 1; d < 64; d <<= 1) {
    s += __shfl_xor(s, d);
    ss += __shfl_xor(ss, d);
  }
  __shared__ float ps[2][2], pq[2][2];
  if ((t & 63) == 0) {
    ps[rloc][t >> 6] = s;
    pq[rloc][t >> 6] = ss;
  }
  __syncthreads();
  s = ps[rloc][0] + ps[rloc][1];
  ss = pq[rloc][0] + pq[rloc][1];
  const float mu = s * (1.0f / 512.0f);
  const float rstd = rsqrtf(ss * (1.0f / 512.0f) - mu * mu + 1e-3f);
  const float4 gv = ((const float4*)gamma)[t];
  const float4 be = ((const float4*)beta)[t];
  float4 y;
  y.x = (x0 - mu) * rstd * gv.x + be.x;
  y.y = (x1 - mu) * rstd * gv.y + be.y;
  y.z = (x2 - mu) * rstd * gv.z + be.z;
  y.w = (x3 - mu) * rstd * gv.w + be.w;
  ((float4*)(of + row * 512))[t] = y;
  if (WB) {
    ushort4 o2;
    o2.x = f2bf(y.x);
    o2.y = f2bf(y.y);
    o2.z = f2bf(y.z);
    o2.w = f2bf(y.w);
    ((ushort4*)(ob + row * 512))[t] = o2;
  }
}

// ---------------------------------------------------------------------------
// Single prologue kernel: 6 weight transposes + x cast + bias concat.
// ---------------------------------------------------------------------------
__global__ __launch_bounds__(256) void prep(
    const float* __restrict__ xq, const float* __restrict__ wq,
    const float* __restrict__ wk, const float* __restrict__ wv,
    const float* __restrict__ wo, const float* __restrict__ w1,
    const float* __restrict__ w2, const float* __restrict__ bq,
    const float* __restrict__ bk, unsigned short* __restrict__ xb,
    unsigned short* __restrict__ wqk_t, unsigned short* __restrict__ wv_t,
    unsigned short* __restrict__ wo_t, unsigned short* __restrict__ w1_t,
    unsigned short* __restrict__ w2_t, float* __restrict__ bqk) {
  __shared__ float tile[32][33];
  int bid = blockIdx.x;
  const int tid = threadIdx.x;
  if (bid < 10240) {  // transpose jobs: in [R][C] fp32 -> out [C][R] bf16
    const float* src;
    unsigned short* dst;
    int R, C, ct, rt;
    if (bid < 2048) {
      src = wq; dst = wqk_t; R = 512; C = 4096; ct = bid % 128; rt = bid / 128;
    } else if (bid < 4096) {
      bid -= 2048;
      src = wk; dst = wqk_t + 4096l * 512; R = 512; C = 4096;
      ct = bid % 128; rt = bid / 128;
    } else if (bid < 6144) {
      bid -= 4096;
      src = wv; dst = wv_t; R = 512; C = 4096; ct = bid % 128; rt = bid / 128;
    } else if (bid < 8192) {
      bid -= 6144;
      src = wo; dst = wo_t; R = 4096; C = 512; ct = bid % 16; rt = bid / 16;
    } else if (bid < 9216) {
      bid -= 8192;
      src = w1; dst = w1_t; R = 512; C = 2048; ct = bid % 64; rt = bid / 64;
    } else {
      bid -= 9216;
      src = w2; dst = w2_t; R = 2048; C = 512; ct = bid % 16; rt = bid / 16;
    }
    const int tx = tid & 31, ty = tid >> 5;
    const int c0 = ct * 32, r0 = rt * 32;
#pragma unroll
    for (int i = 0; i < 4; ++i)
      tile[ty + i * 8][tx] = src[(long)(r0 + ty + i * 8) * C + c0 + tx];
    __syncthreads();
#pragma unroll
    for (int i = 0; i < 4; ++i)
      dst[(long)(c0 + ty + i * 8) * R + r0 + tx] = f2bf(tile[tx][ty + i * 8]);
  } else if (bid < 14336) {  // x fp32 -> bf16 cast
    const int i = (bid - 10240) * 1024 + tid * 4;
    const float4 v = *(const float4*)(xq + i);
    ushort4 o;
    o.x = f2bf(v.x);
    o.y = f2bf(v.y);
    o.z = f2bf(v.z);
    o.w = f2bf(v.w);
    *(ushort4*)(xb + i) = o;
  } else {  // bqk = b_q | b_k concat (8192 floats)
    const int j = (bid - 14336) * 1024 + tid * 4;
    const float4 v =
        (j < 4096) ? *(const float4*)(bq + j) : *(const float4*)(bk + j - 4096);
    *(float4*)(bqk + j) = v;
  }
}

extern "C" void kernel_launch(void* const* d_in, const int* in_sizes, int n_in,
                              void* d_out, int out_size, void* d_ws,
                              size_t ws_size, hipStream_t stream) {
  const float* x = (const float*)d_in[0];
  const float* w_q = (const float*)d_in[1];
  const float* b_q = (const float*)d_in[2];
  const float* w_k = (const float*)d_in[3];
  const float* b_k = (const float*)d_in[4];
  const float* w_v = (const float*)d_in[5];
  const float* b_v = (const float*)d_in[6];
  const float* w_o = (const float*)d_in[7];
  const float* b_o = (const float*)d_in[8];
  const float* w1 = (const float*)d_in[9];
  const float* b1 = (const float*)d_in[10];
  const float* w2 = (const float*)d_in[11];
  const float* b2 = (const float*)d_in[12];
  const float* g1 = (const float*)d_in[13];
  const float* be1 = (const float*)d_in[14];
  const float* g2 = (const float*)d_in[15];
  const float* be2 = (const float*)d_in[16];
  float* out = (float*)d_out;

  char* ws = (char*)d_ws;
  size_t off = 0;
  auto alloc = [&](size_t n) {
    char* p = ws + off;
    off += (n + 255) & ~(size_t)255;
    return p;
  };
  // total ~220 MB (ws_size = 256 MiB)
  unsigned short* xb = (unsigned short*)alloc(8192ll * 512 * 2);       // 8 MB
  unsigned short* wqk_t = (unsigned short*)alloc(8192ll * 512 * 2);    // 8 MB
  unsigned short* wv_t = (unsigned short*)alloc(4096ll * 512 * 2);     // 4 MB
  unsigned short* wo_t = (unsigned short*)alloc(512ll * 4096 * 2);     // 4 MB
  unsigned short* w1_t = (unsigned short*)alloc(2048ll * 512 * 2);     // 2 MB
  unsigned short* w2_t = (unsigned short*)alloc(512ll * 2048 * 2);     // 2 MB
  float* bqk = (float*)alloc(8192ll * 4);                              // 32 KB
  unsigned short* qkb = (unsigned short*)alloc(4096ll * 8192 * 2);     // 64 MB (per group)
  unsigned short* vtb = (unsigned short*)alloc(4ll * 4096 * 1024 * 2); // 32 MB (per group)
  unsigned short* ctxf = (unsigned short*)alloc(8192ll * 4096 * 2);    // 64 MB (full)
  float* proj = (float*)alloc(8192ll * 512 * 4);                       // 16 MB
  unsigned short* projb = xb;      // xb dead after group loop
  unsigned short* h1 = qkb;        // qkb dead after o-proj reduce
  float* pOP = (float*)qkb;        // o-proj split-K partials (4x16 MB = qkb size)
  float* pF2 = (float*)ctxf;       // ffn2 split-K partials (4x16 MB = ctxf size)

  // fused prologue: 6 weight transposes + x cast + bias concat, one launch
  prep<<<14344, 256, 0, stream>>>(x, w_q, w_k, w_v, w_o, w1, w2, b_q, b_k, xb,
                                  wqk_t, wv_t, wo_t, w1_t, w2_t, bqk);

  for (int g = 0; g < 2; ++g) {
    const unsigned short* xg = xb + (long)g * 4096 * 512;
    // fused q|k projection (M=4096, N=8192, K=512) — 256² dbuf, 512 blocks
    gemm_bt2<1, false, true><<<dim3(32, 16, 1), 512, 0, stream>>>(
        xg, wqk_t, qkb, bqk, 512, 512, 512, 8192, 0, 0, 0);
    // v^T = w_v^T @ x^T (M=4096, N=1024/batch, z=4) — 256² dbuf, 256 blocks
    gemm_bt2<2, false, true><<<dim3(4, 16, 4), 512, 0, stream>>>(
        wv_t, xg, vtb, b_v, 512, 512, 512, 1024, 0, 1024ll * 512,
        4096ll * 1024);
    // attention -> ctxf slice; grid (bh=32, qblk=8) for XCD locality
    attn<<<dim3(32, 8), 512, 0, stream>>>(qkb, vtb, ctxf + (long)g * 4096 * 4096);
  }
  // O projection (M=8192, N=512, K=4096) — 256² dbuf, split-K z=4
  // (K-chunk 1024, 16 K-steps), grid (2,32,4) = 256 blocks; fp32 partials.
  gemm_bt2<0, false, false><<<dim3(2, 32, 4), 512, 0, stream>>>(
      ctxf, wo_t, pOP, nullptr, 1024, 4096, 4096, 512, 1024, 1024,
      8192ll * 512);
  // reduce 4 partials + b_o + residual(x) + LN1 -> proj (fp32) + projb (bf16)
  ln_reduce<4, true><<<4096, 256, 0, stream>>>(pOP, 8192ll * 512, b_o, x, g1,
                                               be1, proj, projb);
  // FFN1 (relu, M=8192, N=2048, K=512) — 256² dbuf, 256 blocks
  gemm_bt2<1, true, true><<<dim3(8, 32, 1), 512, 0, stream>>>(
      projb, w1_t, h1, b1, 512, 512, 512, 2048, 0, 0, 0);
  // FFN2 (M=8192, N=512, K=2048) — 256² dbuf, split-K z=4 (K-chunk 512,
  // 8 K-steps), grid (2,32,4) = 256 blocks; fp32 partials in pF2.
  gemm_bt2<0, false, false><<<dim3(2, 32, 4), 512, 0, stream>>>(
      h1, w2_t, pF2, nullptr, 512, 2048, 2048, 512, 512, 512, 8192ll * 512);
  // reduce 4 partials + b2 + residual(proj) + LN2 -> out
  ln_reduce<4, false><<<4096, 256, 0, stream>>>(pF2, 8192ll * 512, b2, proj,
                                                g2, be2, out, nullptr);
}

// Round 12
// 574.870 us; speedup vs baseline: 1.0115x; 1.0115x over previous
//
#include <hip/hip_runtime.h>
#include <stdint.h>

typedef __bf16 bf16_t;
typedef bf16_t bf16x8 __attribute__((ext_vector_type(8)));
typedef float floatx4 __attribute__((ext_vector_type(4)));

__device__ __forceinline__ unsigned short f2bf(float f) {
  union { float f; uint32_t u; } v; v.f = f;
  return (unsigned short)((v.u + 0x7fffu + ((v.u >> 16) & 1u)) >> 16);
}

#define GLD16(g, l)                                                            \
  __builtin_amdgcn_global_load_lds(                                            \
      (const __attribute__((address_space(1))) void*)(g),                      \
      (__attribute__((address_space(3))) void*)(l), 16, 0, 0)

// ---------------------------------------------------------------------------
// GEMM (128x128, single-buffered, 2 barriers/K-step): used for the split-K
// fp32-partial GEMMs (o-proj, ffn2). Round-11's 256²/split-4 conversion of
// these REGRESSED (581 vs 574): 1 block/CU at 128 KB LDS loses the
// co-resident-block overlap, and NP=4 partials add 64 MB of HBM round-trip.
// This 128² split-2 configuration (512 blocks = 2/CU) is the measured best.
// ---------------------------------------------------------------------------
template <int BIAS_MODE, bool RELU, bool OUT_BF16, bool HAS_RESID>
__global__ __launch_bounds__(256) void gemm_bt(
    const unsigned short* __restrict__ A, const unsigned short* __restrict__ Bt,
    void* __restrict__ C, const float* __restrict__ bias,
    const float* __restrict__ resid, int K, int lda, int ldb, int ldc,
    long sA, long sB, long sC, long sR) {
  __shared__ unsigned short As[128 * 64];
  __shared__ unsigned short Bs[128 * 64];
  const int tid = threadIdx.x;
  const int lane = tid & 63;
  const int wave = tid >> 6;
  const unsigned short* Ab = A + blockIdx.z * sA + (long)blockIdx.y * 128 * lda;
  const unsigned short* Bb = Bt + blockIdx.z * sB + (long)blockIdx.x * 128 * ldb;
  const int wm = (wave & 1) << 6;
  const int wn = (wave >> 1) << 6;

  floatx4 acc[4][4] = {};

  const int sr = tid >> 3;  // staging row 0..31 (+32 per issue)
  const int sc = tid & 7;   // staging chunk 0..7

  for (int kt = 0; kt < K; kt += 64) {
#pragma unroll
    for (int i = 0; i < 4; ++i) {
      int r = sr + i * 32;
      int gc = sc ^ (r & 7);
      GLD16(Ab + (long)r * lda + kt + gc * 8, As + (i * 256 + wave * 64) * 8);
    }
#pragma unroll
    for (int i = 0; i < 4; ++i) {
      int r = sr + i * 32;
      int gc = sc ^ (r & 7);
      GLD16(Bb + (long)r * ldb + kt + gc * 8, Bs + (i * 256 + wave * 64) * 8);
    }
    __syncthreads();
#pragma unroll
    for (int ks = 0; ks < 2; ++ks) {
      bf16x8 af[4], bfr[4];
#pragma unroll
      for (int i = 0; i < 4; ++i) {
        int row = wm + i * 16 + (lane & 15);
        int ch = (ks * 4 + (lane >> 4)) ^ (row & 7);
        af[i] = *(const bf16x8*)(As + row * 64 + ch * 8);
      }
#pragma unroll
      for (int j = 0; j < 4; ++j) {
        int row = wn + j * 16 + (lane & 15);
        int ch = (ks * 4 + (lane >> 4)) ^ (row & 7);
        bfr[j] = *(const bf16x8*)(Bs + row * 64 + ch * 8);
      }
#pragma unroll
      for (int i = 0; i < 4; ++i)
#pragma unroll
        for (int j = 0; j < 4; ++j)
          acc[i][j] = __builtin_amdgcn_mfma_f32_16x16x32_bf16(af[i], bfr[j],
                                                              acc[i][j], 0, 0, 0);
    }
    __syncthreads();
  }

  const int rl = (lane >> 4) << 2;
  const int cl = lane & 15;
#pragma unroll
  for (int i = 0; i < 4; ++i) {
#pragma unroll
    for (int j = 0; j < 4; ++j) {
#pragma unroll
      for (int rg = 0; rg < 4; ++rg) {
        int row = (blockIdx.y << 7) + wm + i * 16 + rl + rg;
        int col = (blockIdx.x << 7) + wn + j * 16 + cl;
        float v = acc[i][j][rg];
        if (BIAS_MODE == 1) v += bias[col];
        if (BIAS_MODE == 2) v += bias[row];
        if (HAS_RESID) v += resid[blockIdx.z * sR + (long)row * ldc + col];
        if (RELU) v = fmaxf(v, 0.0f);
        long idx = blockIdx.z * sC + (long)row * ldc + col;
        if (OUT_BF16)
          ((unsigned short*)C)[idx] = f2bf(v);
        else
          ((float*)C)[idx] = v;
      }
    }
  }
}

// ---------------------------------------------------------------------------
// 256x256 double-buffered 2-phase GEMM (verified round-10 win): for the
// bf16-out bias GEMMs with >=256 blocks — qk-proj, v-proj, ffn1.
// 512 thr = 8 waves (2x4), wave tile 128x64, acc[8][4], STAGE(t+1) issued
// before compute, ONE barrier per K-step. LDS 2x64 KB = 128 KB.
// ---------------------------------------------------------------------------
template <int BIAS_MODE, bool RELU>
__global__ __launch_bounds__(512, 2) void gemm_bt2(
    const unsigned short* __restrict__ A, const unsigned short* __restrict__ Bt,
    unsigned short* __restrict__ C, const float* __restrict__ bias, int K,
    int lda, int ldb, int ldc, long sB, long sC) {
  __shared__ unsigned short As[2][256 * 64];
  __shared__ unsigned short Bs[2][256 * 64];
  const int tid = threadIdx.x;
  const int lane = tid & 63;
  const int wave = tid >> 6;        // 0..7
  const unsigned short* Ab = A + (long)blockIdx.y * 256 * lda;
  const unsigned short* Bb = Bt + blockIdx.z * sB + (long)blockIdx.x * 256 * ldb;
  const int wm = (wave & 1) << 7;   // 0/128
  const int wn = (wave >> 1) << 6;  // 0/64/128/192

  floatx4 acc[8][4] = {};

  const int sr = tid >> 3;  // staging row 0..63 (+64 per issue)
  const int sc = tid & 7;   // staging chunk 0..7

  // stage K-tile starting at kt into buffer bf (wave-linear LDS dest,
  // chunk-XOR pre-swizzled global source — both-sides rule)
  auto STAGE = [&](int kt, int bf) {
#pragma unroll
    for (int i = 0; i < 4; ++i) {
      int r = sr + i * 64;
      int gc = sc ^ (r & 7);
      GLD16(Ab + (long)r * lda + kt + gc * 8,
            As[bf] + (i * 512 + wave * 64) * 8);
    }
#pragma unroll
    for (int i = 0; i < 4; ++i) {
      int r = sr + i * 64;
      int gc = sc ^ (r & 7);
      GLD16(Bb + (long)r * ldb + kt + gc * 8,
            Bs[bf] + (i * 512 + wave * 64) * 8);
    }
  };

  STAGE(0, 0);
  __syncthreads();  // drains tile-0 DMA

  const int nt = K >> 6;
  for (int t = 0; t < nt; ++t) {
    // issue next tile's DMA FIRST; it flies under this tile's compute and
    // drains at this step's single end barrier. The destination buffer's
    // last reads completed at the (t-1) end barrier.
    if (t + 1 < nt) STAGE((t + 1) << 6, (t + 1) & 1);
    const unsigned short* Al = As[t & 1];
    const unsigned short* Bl = Bs[t & 1];
#pragma unroll
    for (int ks = 0; ks < 2; ++ks) {
      bf16x8 af[8], bfr[4];
#pragma unroll
      for (int i = 0; i < 8; ++i) {
        int row = wm + i * 16 + (lane & 15);
        int ch = (ks * 4 + (lane >> 4)) ^ (row & 7);
        af[i] = *(const bf16x8*)(Al + row * 64 + ch * 8);
      }
#pragma unroll
      for (int j = 0; j < 4; ++j) {
        int row = wn + j * 16 + (lane & 15);
        int ch = (ks * 4 + (lane >> 4)) ^ (row & 7);
        bfr[j] = *(const bf16x8*)(Bl + row * 64 + ch * 8);
      }
#pragma unroll
      for (int i = 0; i < 8; ++i)
#pragma unroll
        for (int j = 0; j < 4; ++j)
          acc[i][j] = __builtin_amdgcn_mfma_f32_16x16x32_bf16(af[i], bfr[j],
                                                              acc[i][j], 0, 0, 0);
    }
    __syncthreads();  // drains STAGE(t+1) DMA; all reads of buf[t&1] done
  }

  const int rl = (lane >> 4) << 2;
  const int cl = lane & 15;
#pragma unroll
  for (int i = 0; i < 8; ++i) {
#pragma unroll
    for (int j = 0; j < 4; ++j) {
#pragma unroll
      for (int rg = 0; rg < 4; ++rg) {
        int row = (blockIdx.y << 8) + wm + i * 16 + rl + rg;
        int col = (blockIdx.x << 8) + wn + j * 16 + cl;
        float v = acc[i][j][rg];
        if (BIAS_MODE == 1) v += bias[col];
        if (BIAS_MODE == 2) v += bias[row];
        if (RELU) v = fmaxf(v, 0.0f);
        C[blockIdx.z * sC + (long)row * ldc + col] = f2bf(v);
      }
    }
  }
}

// ---------------------------------------------------------------------------
// Flash attention — round-9 version, FROZEN (103.7 µs, conflicts 2.1e6).
// Round-0 pipeline + isolated 4-bit K swizzle (verified win).
// ---------------------------------------------------------------------------
__global__ __launch_bounds__(512, 2) void attn(
    const unsigned short* __restrict__ qk, const unsigned short* __restrict__ vt,
    unsigned short* __restrict__ ctx) {
  __shared__ unsigned short ldsK[2][32 * 512];  // 64 KB, chunk-swizzled rows
  __shared__ unsigned short ldsV[2][32 * 512];  // 64 KB, bank-swizzled slots
  __shared__ unsigned short ldsP[128 * 40];     // 10 KB, pad-40 rows
  __shared__ float ldsL[128];                   // per-row l (final)

  const int tid = threadIdx.x;
  const int lane = tid & 63;
  const int wave = tid >> 6;  // 0..7
  const int quad = lane >> 4;
  const int l15 = lane & 15;
  const int b = blockIdx.x >> 3;  // group-local batch 0..3
  const int h = blockIdx.x & 7;
  const int qblk = blockIdx.y << 7;  // 128-row block base within batch
  const float cs = 0.044194173824159216f * 1.4426950408889634f;  // scale*log2e

  // Q fragments for this wave's 16 S-rows (qblk + wave*16 + l15)
  bf16x8 qf[16];
  {
    const unsigned short* qp =
        qk + (long)(b * 1024 + qblk + wave * 16 + l15) * 8192 + h * 512 +
        (quad << 3);
#pragma unroll
    for (int ks = 0; ks < 16; ++ks) qf[ks] = *(const bf16x8*)(qp + ks * 32);
  }

  floatx4 o[32];  // o[qb*4+db]: rows qb*16+quad*4+reg, cols wave*64+db*16+l15
#pragma unroll
  for (int i = 0; i < 32; ++i) o[i] = floatx4{0.f, 0.f, 0.f, 0.f};
  floatx4 l_i = floatx4{0.f, 0.f, 0.f, 0.f};  // per-lane partial row sums

  // V staging source mapping (lane -> slot lane): d-local = lane>>2,
  // kc = ((lane&3) - (lane>>3)) & 3  (inverse of the read swizzle)
  const int st_d = lane >> 2;
  const int st_kc = ((lane & 3) - (lane >> 3)) & 3;

  // prologue: stage K[0] and V[0]
  {
#pragma unroll
    for (int i = 0; i < 4; ++i) {
      int r = i * 8 + wave;
      int gc = (lane & ~15) | ((lane ^ r) & 15);
      GLD16(qk + (long)(b * 1024 + r) * 8192 + 4096 + h * 512 + gc * 8,
            ldsK[0] + r * 512);
    }
#pragma unroll
    for (int i = 0; i < 4; ++i) {
      int j = i * 8 + wave;
      GLD16(vt + (long)(b * 4096 + h * 512 + j * 16 + st_d) * 1024 + st_kc * 8,
            ldsV[0] + j * 512);
    }
  }
  __syncthreads();  // drains K[0]+V[0] DMA

  for (int kt = 0; kt < 32; ++kt) {
    const unsigned short* kb = ldsK[kt & 1];
    const unsigned short* vb = ldsV[kt & 1];
    // prefetch K[kt+1] and V[kt+1]; drained at this iteration's END barrier
    if (kt + 1 < 32) {
#pragma unroll
      for (int i = 0; i < 4; ++i) {
        int r = i * 8 + wave;
        int gc = (lane & ~15) | ((lane ^ r) & 15);
        GLD16(qk + (long)(b * 1024 + (kt + 1) * 32 + r) * 8192 + 4096 +
                  h * 512 + gc * 8,
              ldsK[(kt + 1) & 1] + r * 512);
      }
#pragma unroll
      for (int i = 0; i < 4; ++i) {
        int j = i * 8 + wave;
        GLD16(vt + (long)(b * 4096 + h * 512 + j * 16 + st_d) * 1024 +
                  (kt + 1) * 32 + st_kc * 8,
              ldsV[(kt + 1) & 1] + j * 512);
      }
    }

    // --- S = Q K^T : this wave's 16 rows x 32 keys (reads kb) ---
    floatx4 s0 = floatx4{0.f, 0.f, 0.f, 0.f}, s1 = floatx4{0.f, 0.f, 0.f, 0.f};
#pragma unroll
    for (int ks = 0; ks < 16; ++ks) {
      int ch = ks * 4 + quad;
      int sw = (ch & ~15) | ((ch ^ l15) & 15);
      bf16x8 k0 = *(const bf16x8*)(kb + l15 * 512 + sw * 8);
      bf16x8 k1 = *(const bf16x8*)(kb + (16 + l15) * 512 + sw * 8);
      s0 = __builtin_amdgcn_mfma_f32_16x16x32_bf16(qf[ks], k0, s0, 0, 0, 0);
      s1 = __builtin_amdgcn_mfma_f32_16x16x32_bf16(qf[ks], k1, s1, 0, 0, 0);
    }

    // --- no-max softmax: p = 2^(s*scale*log2e); accumulate per-lane l ---
    {
      unsigned short* pw = ldsP + wave * 16 * 40;
      const int rb = quad << 2;
#pragma unroll
      for (int r = 0; r < 4; ++r) {
        float e0 = __builtin_amdgcn_exp2f(s0[r] * cs);
        float e1 = __builtin_amdgcn_exp2f(s1[r] * cs);
        l_i[r] += e0 + e1;
        pw[(rb + r) * 40 + l15] = f2bf(e0);
        pw[(rb + r) * 40 + 16 + l15] = f2bf(e1);
      }
    }
    // mid-barrier: LDS-only visibility (P); K/V[kt+1] DMAs stay in flight.
    asm volatile("s_waitcnt lgkmcnt(0)\n\ts_barrier" ::: "memory");

    // --- O += P @ V (d-split: this wave's 64 dims) ---
#pragma unroll
    for (int half = 0; half < 2; ++half) {
      bf16x8 pf[4];
#pragma unroll
      for (int q4 = 0; q4 < 4; ++q4)
        pf[q4] = *(const bf16x8*)(ldsP + ((half * 4 + q4) * 16 + l15) * 40 +
                                  (quad << 3));
#pragma unroll
      for (int db = 0; db < 4; ++db) {
        int n = wave * 4 + db;
        bf16x8 vf = *(const bf16x8*)(
            vb + n * 512 + (l15 * 4 + ((quad + (l15 >> 1)) & 3)) * 8);
#pragma unroll
        for (int q4 = 0; q4 < 4; ++q4)
          o[(half * 4 + q4) * 4 + db] = __builtin_amdgcn_mfma_f32_16x16x32_bf16(
              pf[q4], vf, o[(half * 4 + q4) * 4 + db], 0, 0, 0);
      }
    }
    __syncthreads();  // drains K/V[kt+1] DMA; all LDS reads of kt done
  }

  // final l reduction across the 16 lanes holding each row's partials
#pragma unroll
  for (int r = 0; r < 4; ++r) {
    float rs = l_i[r];
    rs += __shfl_xor(rs, 1);
    rs += __shfl_xor(rs, 2);
    rs += __shfl_xor(rs, 4);
    rs += __shfl_xor(rs, 8);
    if (l15 == 0) ldsL[wave * 16 + (quad << 2) + r] = rs;
  }
  __syncthreads();

#pragma unroll
  for (int qb = 0; qb < 8; ++qb) {
    floatx4 lv = *(const floatx4*)(ldsL + qb * 16 + (quad << 2));
    floatx4 inv;
#pragma unroll
    for (int r = 0; r < 4; ++r) inv[r] = 1.0f / lv[r];
#pragma unroll
    for (int db = 0; db < 4; ++db) {
#pragma unroll
      for (int r = 0; r < 4; ++r) {
        long row = (long)(b * 1024 + qblk + qb * 16 + (quad << 2) + r);
        ctx[row * 4096 + h * 512 + wave * 64 + db * 16 + l15] =
            f2bf(o[qb * 4 + db][r] * inv[r]);
      }
    }
  }
}

// ---------------------------------------------------------------------------
// Fused split-K reduce + bias + residual + LayerNorm over last dim (512).
// float4-vectorized, 2 rows per 256-thread block.
// ---------------------------------------------------------------------------
template <int NP, bool WB>
__global__ __launch_bounds__(256) void ln_reduce(
    const float* __restrict__ p, long sP, const float* __restrict__ bias,
    const float* __restrict__ resid, const float* __restrict__ gamma,
    const float* __restrict__ beta, float* __restrict__ of,
    unsigned short* __restrict__ ob) {
  const int rloc = threadIdx.x >> 7;              // 0..1: row within block
  const long row = (long)blockIdx.x * 2 + rloc;
  const int t = threadIdx.x & 127;                // 0..127: col/4 within row
  float4 a = ((const float4*)(p + row * 512))[t];
#pragma unroll
  for (int i = 1; i < NP; ++i) {
    const float4 ai = ((const float4*)(p + i * sP + row * 512))[t];
    a.x += ai.x;
    a.y += ai.y;
    a.z += ai.z;
    a.w += ai.w;
  }
  const float4 rv = ((const float4*)(resid + row * 512))[t];
  const float4 bv = ((const float4*)bias)[t];
  const float x0 = a.x + bv.x + rv.x;
  const float x1 = a.y + bv.y + rv.y;
  const float x2 = a.z + bv.z + rv.z;
  const float x3 = a.w + bv.w + rv.w;
  float s = x0 + x1 + x2 + x3;
  float ss = x0 * x0 + x1 * x1 + x2 * x2 + x3 * x3;
#pragma unroll
  for (int d = 1; d < 64; d <<= 1) {
    s += __shfl_xor(s, d);
    ss += __shfl_xor(ss, d);
  }
  __shared__ float ps[2][2], pq[2][2];
  if ((t & 63) == 0) {
    ps[rloc][t >> 6] = s;
    pq[rloc][t >> 6] = ss;
  }
  __syncthreads();
  s = ps[rloc][0] + ps[rloc][1];
  ss = pq[rloc][0] + pq[rloc][1];
  const float mu = s * (1.0f / 512.0f);
  const float rstd = rsqrtf(ss * (1.0f / 512.0f) - mu * mu + 1e-3f);
  const float4 gv = ((const float4*)gamma)[t];
  const float4 be = ((const float4*)beta)[t];
  float4 y;
  y.x = (x0 - mu) * rstd * gv.x + be.x;
  y.y = (x1 - mu) * rstd * gv.y + be.y;
  y.z = (x2 - mu) * rstd * gv.z + be.z;
  y.w = (x3 - mu) * rstd * gv.w + be.w;
  ((float4*)(of + row * 512))[t] = y;
  if (WB) {
    ushort4 o2;
    o2.x = f2bf(y.x);
    o2.y = f2bf(y.y);
    o2.z = f2bf(y.z);
    o2.w = f2bf(y.w);
    ((ushort4*)(ob + row * 512))[t] = o2;
  }
}

// ---------------------------------------------------------------------------
// Single prologue kernel: 6 weight transposes + x cast + bias concat.
// ---------------------------------------------------------------------------
__global__ __launch_bounds__(256) void prep(
    const float* __restrict__ xq, const float* __restrict__ wq,
    const float* __restrict__ wk, const float* __restrict__ wv,
    const float* __restrict__ wo, const float* __restrict__ w1,
    const float* __restrict__ w2, const float* __restrict__ bq,
    const float* __restrict__ bk, unsigned short* __restrict__ xb,
    unsigned short* __restrict__ wqk_t, unsigned short* __restrict__ wv_t,
    unsigned short* __restrict__ wo_t, unsigned short* __restrict__ w1_t,
    unsigned short* __restrict__ w2_t, float* __restrict__ bqk) {
  __shared__ float tile[32][33];
  int bid = blockIdx.x;
  const int tid = threadIdx.x;
  if (bid < 10240) {  // transpose jobs: in [R][C] fp32 -> out [C][R] bf16
    const float* src;
    unsigned short* dst;
    int R, C, ct, rt;
    if (bid < 2048) {
      src = wq; dst = wqk_t; R = 512; C = 4096; ct = bid % 128; rt = bid / 128;
    } else if (bid < 4096) {
      bid -= 2048;
      src = wk; dst = wqk_t + 4096l * 512; R = 512; C = 4096;
      ct = bid % 128; rt = bid / 128;
    } else if (bid < 6144) {
      bid -= 4096;
      src = wv; dst = wv_t; R = 512; C = 4096; ct = bid % 128; rt = bid / 128;
    } else if (bid < 8192) {
      bid -= 6144;
      src = wo; dst = wo_t; R = 4096; C = 512; ct = bid % 16; rt = bid / 16;
    } else if (bid < 9216) {
      bid -= 8192;
      src = w1; dst = w1_t; R = 512; C = 2048; ct = bid % 64; rt = bid / 64;
    } else {
      bid -= 9216;
      src = w2; dst = w2_t; R = 2048; C = 512; ct = bid % 16; rt = bid / 16;
    }
    const int tx = tid & 31, ty = tid >> 5;
    const int c0 = ct * 32, r0 = rt * 32;
#pragma unroll
    for (int i = 0; i < 4; ++i)
      tile[ty + i * 8][tx] = src[(long)(r0 + ty + i * 8) * C + c0 + tx];
    __syncthreads();
#pragma unroll
    for (int i = 0; i < 4; ++i)
      dst[(long)(c0 + ty + i * 8) * R + r0 + tx] = f2bf(tile[tx][ty + i * 8]);
  } else if (bid < 14336) {  // x fp32 -> bf16 cast
    const int i = (bid - 10240) * 1024 + tid * 4;
    const float4 v = *(const float4*)(xq + i);
    ushort4 o;
    o.x = f2bf(v.x);
    o.y = f2bf(v.y);
    o.z = f2bf(v.z);
    o.w = f2bf(v.w);
    *(ushort4*)(xb + i) = o;
  } else {  // bqk = b_q | b_k concat (8192 floats)
    const int j = (bid - 14336) * 1024 + tid * 4;
    const float4 v =
        (j < 4096) ? *(const float4*)(bq + j) : *(const float4*)(bk + j - 4096);
    *(float4*)(bqk + j) = v;
  }
}

extern "C" void kernel_launch(void* const* d_in, const int* in_sizes, int n_in,
                              void* d_out, int out_size, void* d_ws,
                              size_t ws_size, hipStream_t stream) {
  const float* x = (const float*)d_in[0];
  const float* w_q = (const float*)d_in[1];
  const float* b_q = (const float*)d_in[2];
  const float* w_k = (const float*)d_in[3];
  const float* b_k = (const float*)d_in[4];
  const float* w_v = (const float*)d_in[5];
  const float* b_v = (const float*)d_in[6];
  const float* w_o = (const float*)d_in[7];
  const float* b_o = (const float*)d_in[8];
  const float* w1 = (const float*)d_in[9];
  const float* b1 = (const float*)d_in[10];
  const float* w2 = (const float*)d_in[11];
  const float* b2 = (const float*)d_in[12];
  const float* g1 = (const float*)d_in[13];
  const float* be1 = (const float*)d_in[14];
  const float* g2 = (const float*)d_in[15];
  const float* be2 = (const float*)d_in[16];
  float* out = (float*)d_out;

  char* ws = (char*)d_ws;
  size_t off = 0;
  auto alloc = [&](size_t n) {
    char* p = ws + off;
    off += (n + 255) & ~(size_t)255;
    return p;
  };
  // total ~220 MB (ws_size = 256 MiB)
  unsigned short* xb = (unsigned short*)alloc(8192ll * 512 * 2);       // 8 MB
  unsigned short* wqk_t = (unsigned short*)alloc(8192ll * 512 * 2);    // 8 MB
  unsigned short* wv_t = (unsigned short*)alloc(4096ll * 512 * 2);     // 4 MB
  unsigned short* wo_t = (unsigned short*)alloc(512ll * 4096 * 2);     // 4 MB
  unsigned short* w1_t = (unsigned short*)alloc(2048ll * 512 * 2);     // 2 MB
  unsigned short* w2_t = (unsigned short*)alloc(512ll * 2048 * 2);     // 2 MB
  float* bqk = (float*)alloc(8192ll * 4);                              // 32 KB
  unsigned short* qkb = (unsigned short*)alloc(4096ll * 8192 * 2);     // 64 MB (per group)
  unsigned short* vtb = (unsigned short*)alloc(4ll * 4096 * 1024 * 2); // 32 MB (per group)
  unsigned short* ctxf = (unsigned short*)alloc(8192ll * 4096 * 2);    // 64 MB (full)
  float* proj = (float*)alloc(8192ll * 512 * 4);                       // 16 MB
  unsigned short* projb = xb;      // xb dead after group loop
  unsigned short* h1 = qkb;        // qkb dead after o-proj reduce
  float* pOP = (float*)qkb;        // o-proj split-K partials (2x16 MB, qkb dead after attn)
  float* pF2 = (float*)ctxf;       // ffn2 split-K partials (2x16 MB, ctxf dead after o-proj)

  // fused prologue: 6 weight transposes + x cast + bias concat, one launch
  prep<<<14344, 256, 0, stream>>>(x, w_q, w_k, w_v, w_o, w1, w2, b_q, b_k, xb,
                                  wqk_t, wv_t, wo_t, w1_t, w2_t, bqk);

  for (int g = 0; g < 2; ++g) {
    const unsigned short* xg = xb + (long)g * 4096 * 512;
    // fused q|k projection (M=4096, N=8192, K=512) — 256² dbuf, 512 blocks
    gemm_bt2<1, false><<<dim3(32, 16, 1), 512, 0, stream>>>(
        xg, wqk_t, qkb, bqk, 512, 512, 512, 8192, 0, 0);
    // v^T = w_v^T @ x^T (M=4096, N=1024/batch, z=4) — 256² dbuf, 256 blocks
    gemm_bt2<2, false><<<dim3(4, 16, 4), 512, 0, stream>>>(
        wv_t, xg, vtb, b_v, 512, 512, 512, 1024, 1024ll * 512, 4096ll * 1024);
    // attention -> ctxf slice; grid (bh=32, qblk=8) for XCD locality
    attn<<<dim3(32, 8), 512, 0, stream>>>(qkb, vtb, ctxf + (long)g * 4096 * 4096);
  }
  // O projection, split-K 2x2048 -> 512 blocks (2/CU, 32 K-steps each)
  gemm_bt<0, false, false, false><<<dim3(4, 64, 2), 256, 0, stream>>>(
      ctxf, wo_t, pOP, nullptr, nullptr, 2048, 4096, 4096, 512, 2048, 2048,
      8192ll * 512, 0);
  // reduce + b_o + residual(x) + LN1 -> proj (fp32) + projb (bf16)
  ln_reduce<2, true><<<4096, 256, 0, stream>>>(pOP, 8192ll * 512, b_o, x, g1,
                                               be1, proj, projb);
  // FFN1 (relu, M=8192, N=2048, K=512) — 256² dbuf, 256 blocks
  gemm_bt2<1, true><<<dim3(8, 32, 1), 512, 0, stream>>>(
      projb, w1_t, h1, b1, 512, 512, 512, 2048, 0, 0);
  // FFN2, split-K 2x1024 -> 512 blocks (2/CU, 16 K-steps); partials in pF2
  gemm_bt<0, false, false, false><<<dim3(4, 64, 2), 256, 0, stream>>>(
      h1, w2_t, pF2, nullptr, nullptr, 1024, 2048, 2048, 512, 1024, 1024,
      8192ll * 512, 0);
  // reduce + b2 + residual(proj) + LN2 -> out
  ln_reduce<2, false><<<4096, 256, 0, stream>>>(pF2, 8192ll * 512, b2, proj,
                                                g2, be2, out, nullptr);
}

// Round 13
// 573.806 us; speedup vs baseline: 1.0134x; 1.0019x over previous
//
#include <hip/hip_runtime.h>
#include <stdint.h>

typedef __bf16 bf16_t;
typedef bf16_t bf16x8 __attribute__((ext_vector_type(8)));
typedef float floatx4 __attribute__((ext_vector_type(4)));

__device__ __forceinline__ unsigned short f2bf(float f) {
  union { float f; uint32_t u; } v; v.f = f;
  return (unsigned short)((v.u + 0x7fffu + ((v.u >> 16) & 1u)) >> 16);
}

#define GLD16(g, l)                                                            \
  __builtin_amdgcn_global_load_lds(                                            \
      (const __attribute__((address_space(1))) void*)(g),                      \
      (__attribute__((address_space(3))) void*)(l), 16, 0, 0)

// ---------------------------------------------------------------------------
// Round-13: group-padded LDS in both GEMM kernels (single mechanism).
// Every GEMM ds_read_b128 had an 8-way bank conflict: rows are 128 B apart
// (bank-neutral), and with 64 lanes over 8 chunk-slots, pigeonhole puts
// 8 lanes (8 distinct rows) on each 16 B bank-group per instruction. The
// chunk-XOR only permutes which rows collide. Fix: each staging DMA writes
// exactly one 8-row x 128 B group, so pad BETWEEN groups (stride 1040 B =
// 520 shorts): each group's banks shift by 4, splitting the (row,row+8)
// pairs -> 8-way becomes 4-way (the irreducible same-group quad aliasing).
// Read addr: (row>>3)*520 + (row&7)*64 + ch*8 shorts. Staging dest:
// group*520. Swizzle algebra, epilogues, grids unchanged.
// ---------------------------------------------------------------------------

// ---------------------------------------------------------------------------
// GEMM (128x128, single-buffered): for the split-K fp32-partial GEMMs
// (o-proj, ffn2; N=512 shapes). 512 blocks = 2/CU config (round-11's
// 256²/split-4 conversion regressed; this is the measured best).
// ---------------------------------------------------------------------------
template <int BIAS_MODE, bool RELU, bool OUT_BF16, bool HAS_RESID>
__global__ __launch_bounds__(256) void gemm_bt(
    const unsigned short* __restrict__ A, const unsigned short* __restrict__ Bt,
    void* __restrict__ C, const float* __restrict__ bias,
    const float* __restrict__ resid, int K, int lda, int ldb, int ldc,
    long sA, long sB, long sC, long sR) {
  __shared__ unsigned short As[16 * 520];  // 16 groups of 8 rows, +16B pad
  __shared__ unsigned short Bs[16 * 520];
  const int tid = threadIdx.x;
  const int lane = tid & 63;
  const int wave = tid >> 6;
  const unsigned short* Ab = A + blockIdx.z * sA + (long)blockIdx.y * 128 * lda;
  const unsigned short* Bb = Bt + blockIdx.z * sB + (long)blockIdx.x * 128 * ldb;
  const int wm = (wave & 1) << 6;
  const int wn = (wave >> 1) << 6;

  floatx4 acc[4][4] = {};

  const int sr = tid >> 3;  // staging row 0..31 (+32 per issue)
  const int sc = tid & 7;   // staging chunk 0..7

  for (int kt = 0; kt < K; kt += 64) {
#pragma unroll
    for (int i = 0; i < 4; ++i) {
      int r = sr + i * 32;
      int gc = sc ^ (r & 7);
      // one instruction = one 8-row group (group index i*4 + wave)
      GLD16(Ab + (long)r * lda + kt + gc * 8, As + (i * 4 + wave) * 520);
    }
#pragma unroll
    for (int i = 0; i < 4; ++i) {
      int r = sr + i * 32;
      int gc = sc ^ (r & 7);
      GLD16(Bb + (long)r * ldb + kt + gc * 8, Bs + (i * 4 + wave) * 520);
    }
    __syncthreads();
#pragma unroll
    for (int ks = 0; ks < 2; ++ks) {
      bf16x8 af[4], bfr[4];
#pragma unroll
      for (int i = 0; i < 4; ++i) {
        int row = wm + i * 16 + (lane & 15);
        int ch = (ks * 4 + (lane >> 4)) ^ (row & 7);
        af[i] = *(const bf16x8*)(As + (row >> 3) * 520 + (row & 7) * 64 + ch * 8);
      }
#pragma unroll
      for (int j = 0; j < 4; ++j) {
        int row = wn + j * 16 + (lane & 15);
        int ch = (ks * 4 + (lane >> 4)) ^ (row & 7);
        bfr[j] = *(const bf16x8*)(Bs + (row >> 3) * 520 + (row & 7) * 64 + ch * 8);
      }
#pragma unroll
      for (int i = 0; i < 4; ++i)
#pragma unroll
        for (int j = 0; j < 4; ++j)
          acc[i][j] = __builtin_amdgcn_mfma_f32_16x16x32_bf16(af[i], bfr[j],
                                                              acc[i][j], 0, 0, 0);
    }
    __syncthreads();
  }

  const int rl = (lane >> 4) << 2;
  const int cl = lane & 15;
#pragma unroll
  for (int i = 0; i < 4; ++i) {
#pragma unroll
    for (int j = 0; j < 4; ++j) {
#pragma unroll
      for (int rg = 0; rg < 4; ++rg) {
        int row = (blockIdx.y << 7) + wm + i * 16 + rl + rg;
        int col = (blockIdx.x << 7) + wn + j * 16 + cl;
        float v = acc[i][j][rg];
        if (BIAS_MODE == 1) v += bias[col];
        if (BIAS_MODE == 2) v += bias[row];
        if (HAS_RESID) v += resid[blockIdx.z * sR + (long)row * ldc + col];
        if (RELU) v = fmaxf(v, 0.0f);
        long idx = blockIdx.z * sC + (long)row * ldc + col;
        if (OUT_BF16)
          ((unsigned short*)C)[idx] = f2bf(v);
        else
          ((float*)C)[idx] = v;
      }
    }
  }
}

// ---------------------------------------------------------------------------
// 256x256 double-buffered 2-phase GEMM: qk-proj, v-proj, ffn1.
// 512 thr = 8 waves (2x4), wave tile 128x64, acc[8][4], STAGE(t+1) before
// compute, ONE barrier per K-step. LDS now 2x2x32x520x2B = 133 KB (1/CU,
// unchanged occupancy).
// ---------------------------------------------------------------------------
template <int BIAS_MODE, bool RELU>
__global__ __launch_bounds__(512, 2) void gemm_bt2(
    const unsigned short* __restrict__ A, const unsigned short* __restrict__ Bt,
    unsigned short* __restrict__ C, const float* __restrict__ bias, int K,
    int lda, int ldb, int ldc, long sB, long sC) {
  __shared__ unsigned short As[2][32 * 520];  // 32 groups of 8 rows, +16B pad
  __shared__ unsigned short Bs[2][32 * 520];
  const int tid = threadIdx.x;
  const int lane = tid & 63;
  const int wave = tid >> 6;        // 0..7
  const unsigned short* Ab = A + (long)blockIdx.y * 256 * lda;
  const unsigned short* Bb = Bt + blockIdx.z * sB + (long)blockIdx.x * 256 * ldb;
  const int wm = (wave & 1) << 7;   // 0/128
  const int wn = (wave >> 1) << 6;  // 0/64/128/192

  floatx4 acc[8][4] = {};

  const int sr = tid >> 3;  // staging row 0..63 (+64 per issue)
  const int sc = tid & 7;   // staging chunk 0..7

  // stage K-tile starting at kt into buffer bf; one instruction = one
  // 8-row group (group index i*8 + wave), dest stride 520 shorts (1040 B).
  auto STAGE = [&](int kt, int bf) {
#pragma unroll
    for (int i = 0; i < 4; ++i) {
      int r = sr + i * 64;
      int gc = sc ^ (r & 7);
      GLD16(Ab + (long)r * lda + kt + gc * 8, As[bf] + (i * 8 + wave) * 520);
    }
#pragma unroll
    for (int i = 0; i < 4; ++i) {
      int r = sr + i * 64;
      int gc = sc ^ (r & 7);
      GLD16(Bb + (long)r * ldb + kt + gc * 8, Bs[bf] + (i * 8 + wave) * 520);
    }
  };

  STAGE(0, 0);
  __syncthreads();  // drains tile-0 DMA

  const int nt = K >> 6;
  for (int t = 0; t < nt; ++t) {
    // issue next tile's DMA FIRST; it flies under this tile's compute and
    // drains at this step's single end barrier.
    if (t + 1 < nt) STAGE((t + 1) << 6, (t + 1) & 1);
    const unsigned short* Al = As[t & 1];
    const unsigned short* Bl = Bs[t & 1];
#pragma unroll
    for (int ks = 0; ks < 2; ++ks) {
      bf16x8 af[8], bfr[4];
#pragma unroll
      for (int i = 0; i < 8; ++i) {
        int row = wm + i * 16 + (lane & 15);
        int ch = (ks * 4 + (lane >> 4)) ^ (row & 7);
        af[i] = *(const bf16x8*)(Al + (row >> 3) * 520 + (row & 7) * 64 + ch * 8);
      }
#pragma unroll
      for (int j = 0; j < 4; ++j) {
        int row = wn + j * 16 + (lane & 15);
        int ch = (ks * 4 + (lane >> 4)) ^ (row & 7);
        bfr[j] = *(const bf16x8*)(Bl + (row >> 3) * 520 + (row & 7) * 64 + ch * 8);
      }
#pragma unroll
      for (int i = 0; i < 8; ++i)
#pragma unroll
        for (int j = 0; j < 4; ++j)
          acc[i][j] = __builtin_amdgcn_mfma_f32_16x16x32_bf16(af[i], bfr[j],
                                                              acc[i][j], 0, 0, 0);
    }
    __syncthreads();  // drains STAGE(t+1) DMA; all reads of buf[t&1] done
  }

  const int rl = (lane >> 4) << 2;
  const int cl = lane & 15;
#pragma unroll
  for (int i = 0; i < 8; ++i) {
#pragma unroll
    for (int j = 0; j < 4; ++j) {
#pragma unroll
      for (int rg = 0; rg < 4; ++rg) {
        int row = (blockIdx.y << 8) + wm + i * 16 + rl + rg;
        int col = (blockIdx.x << 8) + wn + j * 16 + cl;
        float v = acc[i][j][rg];
        if (BIAS_MODE == 1) v += bias[col];
        if (BIAS_MODE == 2) v += bias[row];
        if (RELU) v = fmaxf(v, 0.0f);
        C[blockIdx.z * sC + (long)row * ldc + col] = f2bf(v);
      }
    }
  }
}

// ---------------------------------------------------------------------------
// Flash attention — round-9 version, FROZEN (103.7 µs, conflicts 2.1e6).
// Round-0 pipeline + isolated 4-bit K swizzle (verified win).
// ---------------------------------------------------------------------------
__global__ __launch_bounds__(512, 2) void attn(
    const unsigned short* __restrict__ qk, const unsigned short* __restrict__ vt,
    unsigned short* __restrict__ ctx) {
  __shared__ unsigned short ldsK[2][32 * 512];  // 64 KB, chunk-swizzled rows
  __shared__ unsigned short ldsV[2][32 * 512];  // 64 KB, bank-swizzled slots
  __shared__ unsigned short ldsP[128 * 40];     // 10 KB, pad-40 rows
  __shared__ float ldsL[128];                   // per-row l (final)

  const int tid = threadIdx.x;
  const int lane = tid & 63;
  const int wave = tid >> 6;  // 0..7
  const int quad = lane >> 4;
  const int l15 = lane & 15;
  const int b = blockIdx.x >> 3;  // group-local batch 0..3
  const int h = blockIdx.x & 7;
  const int qblk = blockIdx.y << 7;  // 128-row block base within batch
  const float cs = 0.044194173824159216f * 1.4426950408889634f;  // scale*log2e

  // Q fragments for this wave's 16 S-rows (qblk + wave*16 + l15)
  bf16x8 qf[16];
  {
    const unsigned short* qp =
        qk + (long)(b * 1024 + qblk + wave * 16 + l15) * 8192 + h * 512 +
        (quad << 3);
#pragma unroll
    for (int ks = 0; ks < 16; ++ks) qf[ks] = *(const bf16x8*)(qp + ks * 32);
  }

  floatx4 o[32];  // o[qb*4+db]: rows qb*16+quad*4+reg, cols wave*64+db*16+l15
#pragma unroll
  for (int i = 0; i < 32; ++i) o[i] = floatx4{0.f, 0.f, 0.f, 0.f};
  floatx4 l_i = floatx4{0.f, 0.f, 0.f, 0.f};  // per-lane partial row sums

  // V staging source mapping (lane -> slot lane): d-local = lane>>2,
  // kc = ((lane&3) - (lane>>3)) & 3  (inverse of the read swizzle)
  const int st_d = lane >> 2;
  const int st_kc = ((lane & 3) - (lane >> 3)) & 3;

  // prologue: stage K[0] and V[0]
  {
#pragma unroll
    for (int i = 0; i < 4; ++i) {
      int r = i * 8 + wave;
      int gc = (lane & ~15) | ((lane ^ r) & 15);
      GLD16(qk + (long)(b * 1024 + r) * 8192 + 4096 + h * 512 + gc * 8,
            ldsK[0] + r * 512);
    }
#pragma unroll
    for (int i = 0; i < 4; ++i) {
      int j = i * 8 + wave;
      GLD16(vt + (long)(b * 4096 + h * 512 + j * 16 + st_d) * 1024 + st_kc * 8,
            ldsV[0] + j * 512);
    }
  }
  __syncthreads();  // drains K[0]+V[0] DMA

  for (int kt = 0; kt < 32; ++kt) {
    const unsigned short* kb = ldsK[kt & 1];
    const unsigned short* vb = ldsV[kt & 1];
    // prefetch K[kt+1] and V[kt+1]; drained at this iteration's END barrier
    if (kt + 1 < 32) {
#pragma unroll
      for (int i = 0; i < 4; ++i) {
        int r = i * 8 + wave;
        int gc = (lane & ~15) | ((lane ^ r) & 15);
        GLD16(qk + (long)(b * 1024 + (kt + 1) * 32 + r) * 8192 + 4096 +
                  h * 512 + gc * 8,
              ldsK[(kt + 1) & 1] + r * 512);
      }
#pragma unroll
      for (int i = 0; i < 4; ++i) {
        int j = i * 8 + wave;
        GLD16(vt + (long)(b * 4096 + h * 512 + j * 16 + st_d) * 1024 +
                  (kt + 1) * 32 + st_kc * 8,
              ldsV[(kt + 1) & 1] + j * 512);
      }
    }

    // --- S = Q K^T : this wave's 16 rows x 32 keys (reads kb) ---
    floatx4 s0 = floatx4{0.f, 0.f, 0.f, 0.f}, s1 = floatx4{0.f, 0.f, 0.f, 0.f};
#pragma unroll
    for (int ks = 0; ks < 16; ++ks) {
      int ch = ks * 4 + quad;
      int sw = (ch & ~15) | ((ch ^ l15) & 15);
      bf16x8 k0 = *(const bf16x8*)(kb + l15 * 512 + sw * 8);
      bf16x8 k1 = *(const bf16x8*)(kb + (16 + l15) * 512 + sw * 8);
      s0 = __builtin_amdgcn_mfma_f32_16x16x32_bf16(qf[ks], k0, s0, 0, 0, 0);
      s1 = __builtin_amdgcn_mfma_f32_16x16x32_bf16(qf[ks], k1, s1, 0, 0, 0);
    }

    // --- no-max softmax: p = 2^(s*scale*log2e); accumulate per-lane l ---
    {
      unsigned short* pw = ldsP + wave * 16 * 40;
      const int rb = quad << 2;
#pragma unroll
      for (int r = 0; r < 4; ++r) {
        float e0 = __builtin_amdgcn_exp2f(s0[r] * cs);
        float e1 = __builtin_amdgcn_exp2f(s1[r] * cs);
        l_i[r] += e0 + e1;
        pw[(rb + r) * 40 + l15] = f2bf(e0);
        pw[(rb + r) * 40 + 16 + l15] = f2bf(e1);
      }
    }
    // mid-barrier: LDS-only visibility (P); K/V[kt+1] DMAs stay in flight.
    asm volatile("s_waitcnt lgkmcnt(0)\n\ts_barrier" ::: "memory");

    // --- O += P @ V (d-split: this wave's 64 dims) ---
#pragma unroll
    for (int half = 0; half < 2; ++half) {
      bf16x8 pf[4];
#pragma unroll
      for (int q4 = 0; q4 < 4; ++q4)
        pf[q4] = *(const bf16x8*)(ldsP + ((half * 4 + q4) * 16 + l15) * 40 +
                                  (quad << 3));
#pragma unroll
      for (int db = 0; db < 4; ++db) {
        int n = wave * 4 + db;
        bf16x8 vf = *(const bf16x8*)(
            vb + n * 512 + (l15 * 4 + ((quad + (l15 >> 1)) & 3)) * 8);
#pragma unroll
        for (int q4 = 0; q4 < 4; ++q4)
          o[(half * 4 + q4) * 4 + db] = __builtin_amdgcn_mfma_f32_16x16x32_bf16(
              pf[q4], vf, o[(half * 4 + q4) * 4 + db], 0, 0, 0);
      }
    }
    __syncthreads();  // drains K/V[kt+1] DMA; all LDS reads of kt done
  }

  // final l reduction across the 16 lanes holding each row's partials
#pragma unroll
  for (int r = 0; r < 4; ++r) {
    float rs = l_i[r];
    rs += __shfl_xor(rs, 1);
    rs += __shfl_xor(rs, 2);
    rs += __shfl_xor(rs, 4);
    rs += __shfl_xor(rs, 8);
    if (l15 == 0) ldsL[wave * 16 + (quad << 2) + r] = rs;
  }
  __syncthreads();

#pragma unroll
  for (int qb = 0; qb < 8; ++qb) {
    floatx4 lv = *(const floatx4*)(ldsL + qb * 16 + (quad << 2));
    floatx4 inv;
#pragma unroll
    for (int r = 0; r < 4; ++r) inv[r] = 1.0f / lv[r];
#pragma unroll
    for (int db = 0; db < 4; ++db) {
#pragma unroll
      for (int r = 0; r < 4; ++r) {
        long row = (long)(b * 1024 + qblk + qb * 16 + (quad << 2) + r);
        ctx[row * 4096 + h * 512 + wave * 64 + db * 16 + l15] =
            f2bf(o[qb * 4 + db][r] * inv[r]);
      }
    }
  }
}

// ---------------------------------------------------------------------------
// Fused split-K reduce + bias + residual + LayerNorm over last dim (512).
// float4-vectorized, 2 rows per 256-thread block.
// ---------------------------------------------------------------------------
template <int NP, bool WB>
__global__ __launch_bounds__(256) void ln_reduce(
    const float* __restrict__ p, long sP, const float* __restrict__ bias,
    const float* __restrict__ resid, const float* __restrict__ gamma,
    const float* __restrict__ beta, float* __restrict__ of,
    unsigned short* __restrict__ ob) {
  const int rloc = threadIdx.x >> 7;              // 0..1: row within block
  const long row = (long)blockIdx.x * 2 + rloc;
  const int t = threadIdx.x & 127;                // 0..127: col/4 within row
  float4 a = ((const float4*)(p + row * 512))[t];
#pragma unroll
  for (int i = 1; i < NP; ++i) {
    const float4 ai = ((const float4*)(p + i * sP + row * 512))[t];
    a.x += ai.x;
    a.y += ai.y;
    a.z += ai.z;
    a.w += ai.w;
  }
  const float4 rv = ((const float4*)(resid + row * 512))[t];
  const float4 bv = ((const float4*)bias)[t];
  const float x0 = a.x + bv.x + rv.x;
  const float x1 = a.y + bv.y + rv.y;
  const float x2 = a.z + bv.z + rv.z;
  const float x3 = a.w + bv.w + rv.w;
  float s = x0 + x1 + x2 + x3;
  float ss = x0 * x0 + x1 * x1 + x2 * x2 + x3 * x3;
#pragma unroll
  for (int d = 1; d < 64; d <<= 1) {
    s += __shfl_xor(s, d);
    ss += __shfl_xor(ss, d);
  }
  __shared__ float ps[2][2], pq[2][2];
  if ((t & 63) == 0) {
    ps[rloc][t >> 6] = s;
    pq[rloc][t >> 6] = ss;
  }
  __syncthreads();
  s = ps[rloc][0] + ps[rloc][1];
  ss = pq[rloc][0] + pq[rloc][1];
  const float mu = s * (1.0f / 512.0f);
  const float rstd = rsqrtf(ss * (1.0f / 512.0f) - mu * mu + 1e-3f);
  const float4 gv = ((const float4*)gamma)[t];
  const float4 be = ((const float4*)beta)[t];
  float4 y;
  y.x = (x0 - mu) * rstd * gv.x + be.x;
  y.y = (x1 - mu) * rstd * gv.y + be.y;
  y.z = (x2 - mu) * rstd * gv.z + be.z;
  y.w = (x3 - mu) * rstd * gv.w + be.w;
  ((float4*)(of + row * 512))[t] = y;
  if (WB) {
    ushort4 o2;
    o2.x = f2bf(y.x);
    o2.y = f2bf(y.y);
    o2.z = f2bf(y.z);
    o2.w = f2bf(y.w);
    ((ushort4*)(ob + row * 512))[t] = o2;
  }
}

// ---------------------------------------------------------------------------
// Single prologue kernel: 6 weight transposes + x cast + bias concat.
// ---------------------------------------------------------------------------
__global__ __launch_bounds__(256) void prep(
    const float* __restrict__ xq, const float* __restrict__ wq,
    const float* __restrict__ wk, const float* __restrict__ wv,
    const float* __restrict__ wo, const float* __restrict__ w1,
    const float* __restrict__ w2, const float* __restrict__ bq,
    const float* __restrict__ bk, unsigned short* __restrict__ xb,
    unsigned short* __restrict__ wqk_t, unsigned short* __restrict__ wv_t,
    unsigned short* __restrict__ wo_t, unsigned short* __restrict__ w1_t,
    unsigned short* __restrict__ w2_t, float* __restrict__ bqk) {
  __shared__ float tile[32][33];
  int bid = blockIdx.x;
  const int tid = threadIdx.x;
  if (bid < 10240) {  // transpose jobs: in [R][C] fp32 -> out [C][R] bf16
    const float* src;
    unsigned short* dst;
    int R, C, ct, rt;
    if (bid < 2048) {
      src = wq; dst = wqk_t; R = 512; C = 4096; ct = bid % 128; rt = bid / 128;
    } else if (bid < 4096) {
      bid -= 2048;
      src = wk; dst = wqk_t + 4096l * 512; R = 512; C = 4096;
      ct = bid % 128; rt = bid / 128;
    } else if (bid < 6144) {
      bid -= 4096;
      src = wv; dst = wv_t; R = 512; C = 4096; ct = bid % 128; rt = bid / 128;
    } else if (bid < 8192) {
      bid -= 6144;
      src = wo; dst = wo_t; R = 4096; C = 512; ct = bid % 16; rt = bid / 16;
    } else if (bid < 9216) {
      bid -= 8192;
      src = w1; dst = w1_t; R = 512; C = 2048; ct = bid % 64; rt = bid / 64;
    } else {
      bid -= 9216;
      src = w2; dst = w2_t; R = 2048; C = 512; ct = bid % 16; rt = bid / 16;
    }
    const int tx = tid & 31, ty = tid >> 5;
    const int c0 = ct * 32, r0 = rt * 32;
#pragma unroll
    for (int i = 0; i < 4; ++i)
      tile[ty + i * 8][tx] = src[(long)(r0 + ty + i * 8) * C + c0 + tx];
    __syncthreads();
#pragma unroll
    for (int i = 0; i < 4; ++i)
      dst[(long)(c0 + ty + i * 8) * R + r0 + tx] = f2bf(tile[tx][ty + i * 8]);
  } else if (bid < 14336) {  // x fp32 -> bf16 cast
    const int i = (bid - 10240) * 1024 + tid * 4;
    const float4 v = *(const float4*)(xq + i);
    ushort4 o;
    o.x = f2bf(v.x);
    o.y = f2bf(v.y);
    o.z = f2bf(v.z);
    o.w = f2bf(v.w);
    *(ushort4*)(xb + i) = o;
  } else {  // bqk = b_q | b_k concat (8192 floats)
    const int j = (bid - 14336) * 1024 + tid * 4;
    const float4 v =
        (j < 4096) ? *(const float4*)(bq + j) : *(const float4*)(bk + j - 4096);
    *(float4*)(bqk + j) = v;
  }
}

extern "C" void kernel_launch(void* const* d_in, const int* in_sizes, int n_in,
                              void* d_out, int out_size, void* d_ws,
                              size_t ws_size, hipStream_t stream) {
  const float* x = (const float*)d_in[0];
  const float* w_q = (const float*)d_in[1];
  const float* b_q = (const float*)d_in[2];
  const float* w_k = (const float*)d_in[3];
  const float* b_k = (const float*)d_in[4];
  const float* w_v = (const float*)d_in[5];
  const float* b_v = (const float*)d_in[6];
  const float* w_o = (const float*)d_in[7];
  const float* b_o = (const float*)d_in[8];
  const float* w1 = (const float*)d_in[9];
  const float* b1 = (const float*)d_in[10];
  const float* w2 = (const float*)d_in[11];
  const float* b2 = (const float*)d_in[12];
  const float* g1 = (const float*)d_in[13];
  const float* be1 = (const float*)d_in[14];
  const float* g2 = (const float*)d_in[15];
  const float* be2 = (const float*)d_in[16];
  float* out = (float*)d_out;

  char* ws = (char*)d_ws;
  size_t off = 0;
  auto alloc = [&](size_t n) {
    char* p = ws + off;
    off += (n + 255) & ~(size_t)255;
    return p;
  };
  // total ~220 MB (ws_size = 256 MiB)
  unsigned short* xb = (unsigned short*)alloc(8192ll * 512 * 2);       // 8 MB
  unsigned short* wqk_t = (unsigned short*)alloc(8192ll * 512 * 2);    // 8 MB
  unsigned short* wv_t = (unsigned short*)alloc(4096ll * 512 * 2);     // 4 MB
  unsigned short* wo_t = (unsigned short*)alloc(512ll * 4096 * 2);     // 4 MB
  unsigned short* w1_t = (unsigned short*)alloc(2048ll * 512 * 2);     // 2 MB
  unsigned short* w2_t = (unsigned short*)alloc(512ll * 2048 * 2);     // 2 MB
  float* bqk = (float*)alloc(8192ll * 4);                              // 32 KB
  unsigned short* qkb = (unsigned short*)alloc(4096ll * 8192 * 2);     // 64 MB (per group)
  unsigned short* vtb = (unsigned short*)alloc(4ll * 4096 * 1024 * 2); // 32 MB (per group)
  unsigned short* ctxf = (unsigned short*)alloc(8192ll * 4096 * 2);    // 64 MB (full)
  float* proj = (float*)alloc(8192ll * 512 * 4);                       // 16 MB
  unsigned short* projb = xb;      // xb dead after group loop
  unsigned short* h1 = qkb;        // qkb dead after o-proj reduce
  float* pOP = (float*)qkb;        // o-proj split-K partials (2x16 MB, qkb dead after attn)
  float* pF2 = (float*)ctxf;       // ffn2 split-K partials (2x16 MB, ctxf dead after o-proj)

  // fused prologue: 6 weight transposes + x cast + bias concat, one launch
  prep<<<14344, 256, 0, stream>>>(x, w_q, w_k, w_v, w_o, w1, w2, b_q, b_k, xb,
                                  wqk_t, wv_t, wo_t, w1_t, w2_t, bqk);

  for (int g = 0; g < 2; ++g) {
    const unsigned short* xg = xb + (long)g * 4096 * 512;
    // fused q|k projection (M=4096, N=8192, K=512) — 256² dbuf, 512 blocks
    gemm_bt2<1, false><<<dim3(32, 16, 1), 512, 0, stream>>>(
        xg, wqk_t, qkb, bqk, 512, 512, 512, 8192, 0, 0);
    // v^T = w_v^T @ x^T (M=4096, N=1024/batch, z=4) — 256² dbuf, 256 blocks
    gemm_bt2<2, false><<<dim3(4, 16, 4), 512, 0, stream>>>(
        wv_t, xg, vtb, b_v, 512, 512, 512, 1024, 1024ll * 512, 4096ll * 1024);
    // attention -> ctxf slice; grid (bh=32, qblk=8) for XCD locality
    attn<<<dim3(32, 8), 512, 0, stream>>>(qkb, vtb, ctxf + (long)g * 4096 * 4096);
  }
  // O projection, split-K 2x2048 -> 512 blocks (2/CU, 32 K-steps each)
  gemm_bt<0, false, false, false><<<dim3(4, 64, 2), 256, 0, stream>>>(
      ctxf, wo_t, pOP, nullptr, nullptr, 2048, 4096, 4096, 512, 2048, 2048,
      8192ll * 512, 0);
  // reduce + b_o + residual(x) + LN1 -> proj (fp32) + projb (bf16)
  ln_reduce<2, true><<<4096, 256, 0, stream>>>(pOP, 8192ll * 512, b_o, x, g1,
                                               be1, proj, projb);
  // FFN1 (relu, M=8192, N=2048, K=512) — 256² dbuf, 256 blocks
  gemm_bt2<1, true><<<dim3(8, 32, 1), 512, 0, stream>>>(
      projb, w1_t, h1, b1, 512, 512, 512, 2048, 0, 0);
  // FFN2, split-K 2x1024 -> 512 blocks (2/CU, 16 K-steps); partials in pF2
  gemm_bt<0, false, false, false><<<dim3(4, 64, 2), 256, 0, stream>>>(
      h1, w2_t, pF2, nullptr, nullptr, 1024, 2048, 2048, 512, 1024, 1024,
      8192ll * 512, 0);
  // reduce + b2 + residual(proj) + LN2 -> out
  ln_reduce<2, false><<<4096, 256, 0, stream>>>(pF2, 8192ll * 512, b2, proj,
                                                g2, be2, out, nullptr);
}

// Round 14
// 571.693 us; speedup vs baseline: 1.0171x; 1.0037x over previous
//
#include <hip/hip_runtime.h>
#include <stdint.h>

typedef __bf16 bf16_t;
typedef bf16_t bf16x8 __attribute__((ext_vector_type(8)));
typedef float floatx4 __attribute__((ext_vector_type(4)));

__device__ __forceinline__ unsigned short f2bf(float f) {
  union { float f; uint32_t u; } v; v.f = f;
  return (unsigned short)((v.u + 0x7fffu + ((v.u >> 16) & 1u)) >> 16);
}

#define GLD16(g, l)                                                            \
  __builtin_amdgcn_global_load_lds(                                            \
      (const __attribute__((address_space(1))) void*)(g),                      \
      (__attribute__((address_space(3))) void*)(l), 16, 0, 0)

// ---------------------------------------------------------------------------
// Round-14: double-buffer the 128x128 GEMM (single isolated factor).
// Round-10 proved the dbuf/1-barrier-per-K-step structure on 256² (+22 µs);
// round-11's regression was the BUNDLE (256² tile + split-4 + 1 block/CU),
// not the dbuf mechanism. Here o-proj/ffn2 keep tile 128², split-K 2, grid
// 512 = 2 blocks/CU (LDS 2x33.3 = 66.6 KB -> still 2/CU) and gain only the
// bt2 loop: STAGE(t+1) issued before compute, ONE barrier per K-step, DMA
// flies under MFMA instead of draining into it. Group-padded LDS (round-13,
// verified-correct, perf-null) retained in both kernels.
// ---------------------------------------------------------------------------
template <int BIAS_MODE, bool RELU, bool OUT_BF16, bool HAS_RESID>
__global__ __launch_bounds__(256) void gemm_bt(
    const unsigned short* __restrict__ A, const unsigned short* __restrict__ Bt,
    void* __restrict__ C, const float* __restrict__ bias,
    const float* __restrict__ resid, int K, int lda, int ldb, int ldc,
    long sA, long sB, long sC, long sR) {
  __shared__ unsigned short As[2][16 * 520];  // 2 x 16 groups of 8 rows (+pad)
  __shared__ unsigned short Bs[2][16 * 520];
  const int tid = threadIdx.x;
  const int lane = tid & 63;
  const int wave = tid >> 6;
  const unsigned short* Ab = A + blockIdx.z * sA + (long)blockIdx.y * 128 * lda;
  const unsigned short* Bb = Bt + blockIdx.z * sB + (long)blockIdx.x * 128 * ldb;
  const int wm = (wave & 1) << 6;
  const int wn = (wave >> 1) << 6;

  floatx4 acc[4][4] = {};

  const int sr = tid >> 3;  // staging row 0..31 (+32 per issue)
  const int sc = tid & 7;   // staging chunk 0..7

  auto STAGE = [&](int kt, int bf) {
#pragma unroll
    for (int i = 0; i < 4; ++i) {
      int r = sr + i * 32;
      int gc = sc ^ (r & 7);
      GLD16(Ab + (long)r * lda + kt + gc * 8, As[bf] + (i * 4 + wave) * 520);
    }
#pragma unroll
    for (int i = 0; i < 4; ++i) {
      int r = sr + i * 32;
      int gc = sc ^ (r & 7);
      GLD16(Bb + (long)r * ldb + kt + gc * 8, Bs[bf] + (i * 4 + wave) * 520);
    }
  };

  STAGE(0, 0);
  __syncthreads();  // drains tile-0 DMA

  const int nt = K >> 6;
  for (int t = 0; t < nt; ++t) {
    // issue next tile's DMA FIRST; it flies under this tile's compute and
    // drains at this step's single end barrier. The destination buffer's
    // last reads completed at the (t-1) end barrier.
    if (t + 1 < nt) STAGE((t + 1) << 6, (t + 1) & 1);
    const unsigned short* Al = As[t & 1];
    const unsigned short* Bl = Bs[t & 1];
#pragma unroll
    for (int ks = 0; ks < 2; ++ks) {
      bf16x8 af[4], bfr[4];
#pragma unroll
      for (int i = 0; i < 4; ++i) {
        int row = wm + i * 16 + (lane & 15);
        int ch = (ks * 4 + (lane >> 4)) ^ (row & 7);
        af[i] = *(const bf16x8*)(Al + (row >> 3) * 520 + (row & 7) * 64 + ch * 8);
      }
#pragma unroll
      for (int j = 0; j < 4; ++j) {
        int row = wn + j * 16 + (lane & 15);
        int ch = (ks * 4 + (lane >> 4)) ^ (row & 7);
        bfr[j] = *(const bf16x8*)(Bl + (row >> 3) * 520 + (row & 7) * 64 + ch * 8);
      }
#pragma unroll
      for (int i = 0; i < 4; ++i)
#pragma unroll
        for (int j = 0; j < 4; ++j)
          acc[i][j] = __builtin_amdgcn_mfma_f32_16x16x32_bf16(af[i], bfr[j],
                                                              acc[i][j], 0, 0, 0);
    }
    __syncthreads();  // drains STAGE(t+1) DMA; all reads of buf[t&1] done
  }

  const int rl = (lane >> 4) << 2;
  const int cl = lane & 15;
#pragma unroll
  for (int i = 0; i < 4; ++i) {
#pragma unroll
    for (int j = 0; j < 4; ++j) {
#pragma unroll
      for (int rg = 0; rg < 4; ++rg) {
        int row = (blockIdx.y << 7) + wm + i * 16 + rl + rg;
        int col = (blockIdx.x << 7) + wn + j * 16 + cl;
        float v = acc[i][j][rg];
        if (BIAS_MODE == 1) v += bias[col];
        if (BIAS_MODE == 2) v += bias[row];
        if (HAS_RESID) v += resid[blockIdx.z * sR + (long)row * ldc + col];
        if (RELU) v = fmaxf(v, 0.0f);
        long idx = blockIdx.z * sC + (long)row * ldc + col;
        if (OUT_BF16)
          ((unsigned short*)C)[idx] = f2bf(v);
        else
          ((float*)C)[idx] = v;
      }
    }
  }
}

// ---------------------------------------------------------------------------
// 256x256 double-buffered 2-phase GEMM: qk-proj, v-proj, ffn1.
// 512 thr = 8 waves (2x4), wave tile 128x64, acc[8][4], STAGE(t+1) before
// compute, ONE barrier per K-step. LDS 2x2x32x520x2B = 133 KB (1 block/CU).
// ---------------------------------------------------------------------------
template <int BIAS_MODE, bool RELU>
__global__ __launch_bounds__(512, 2) void gemm_bt2(
    const unsigned short* __restrict__ A, const unsigned short* __restrict__ Bt,
    unsigned short* __restrict__ C, const float* __restrict__ bias, int K,
    int lda, int ldb, int ldc, long sB, long sC) {
  __shared__ unsigned short As[2][32 * 520];  // 32 groups of 8 rows, +16B pad
  __shared__ unsigned short Bs[2][32 * 520];
  const int tid = threadIdx.x;
  const int lane = tid & 63;
  const int wave = tid >> 6;        // 0..7
  const unsigned short* Ab = A + (long)blockIdx.y * 256 * lda;
  const unsigned short* Bb = Bt + blockIdx.z * sB + (long)blockIdx.x * 256 * ldb;
  const int wm = (wave & 1) << 7;   // 0/128
  const int wn = (wave >> 1) << 6;  // 0/64/128/192

  floatx4 acc[8][4] = {};

  const int sr = tid >> 3;  // staging row 0..63 (+64 per issue)
  const int sc = tid & 7;   // staging chunk 0..7

  auto STAGE = [&](int kt, int bf) {
#pragma unroll
    for (int i = 0; i < 4; ++i) {
      int r = sr + i * 64;
      int gc = sc ^ (r & 7);
      GLD16(Ab + (long)r * lda + kt + gc * 8, As[bf] + (i * 8 + wave) * 520);
    }
#pragma unroll
    for (int i = 0; i < 4; ++i) {
      int r = sr + i * 64;
      int gc = sc ^ (r & 7);
      GLD16(Bb + (long)r * ldb + kt + gc * 8, Bs[bf] + (i * 8 + wave) * 520);
    }
  };

  STAGE(0, 0);
  __syncthreads();  // drains tile-0 DMA

  const int nt = K >> 6;
  for (int t = 0; t < nt; ++t) {
    if (t + 1 < nt) STAGE((t + 1) << 6, (t + 1) & 1);
    const unsigned short* Al = As[t & 1];
    const unsigned short* Bl = Bs[t & 1];
#pragma unroll
    for (int ks = 0; ks < 2; ++ks) {
      bf16x8 af[8], bfr[4];
#pragma unroll
      for (int i = 0; i < 8; ++i) {
        int row = wm + i * 16 + (lane & 15);
        int ch = (ks * 4 + (lane >> 4)) ^ (row & 7);
        af[i] = *(const bf16x8*)(Al + (row >> 3) * 520 + (row & 7) * 64 + ch * 8);
      }
#pragma unroll
      for (int j = 0; j < 4; ++j) {
        int row = wn + j * 16 + (lane & 15);
        int ch = (ks * 4 + (lane >> 4)) ^ (row & 7);
        bfr[j] = *(const bf16x8*)(Bl + (row >> 3) * 520 + (row & 7) * 64 + ch * 8);
      }
#pragma unroll
      for (int i = 0; i < 8; ++i)
#pragma unroll
        for (int j = 0; j < 4; ++j)
          acc[i][j] = __builtin_amdgcn_mfma_f32_16x16x32_bf16(af[i], bfr[j],
                                                              acc[i][j], 0, 0, 0);
    }
    __syncthreads();  // drains STAGE(t+1) DMA; all reads of buf[t&1] done
  }

  const int rl = (lane >> 4) << 2;
  const int cl = lane & 15;
#pragma unroll
  for (int i = 0; i < 8; ++i) {
#pragma unroll
    for (int j = 0; j < 4; ++j) {
#pragma unroll
      for (int rg = 0; rg < 4; ++rg) {
        int row = (blockIdx.y << 8) + wm + i * 16 + rl + rg;
        int col = (blockIdx.x << 8) + wn + j * 16 + cl;
        float v = acc[i][j][rg];
        if (BIAS_MODE == 1) v += bias[col];
        if (BIAS_MODE == 2) v += bias[row];
        if (RELU) v = fmaxf(v, 0.0f);
        C[blockIdx.z * sC + (long)row * ldc + col] = f2bf(v);
      }
    }
  }
}

// ---------------------------------------------------------------------------
// Flash attention — round-9 version, FROZEN (103.7 µs, conflicts 2.1e6).
// Round-0 pipeline + isolated 4-bit K swizzle (verified win).
// ---------------------------------------------------------------------------
__global__ __launch_bounds__(512, 2) void attn(
    const unsigned short* __restrict__ qk, const unsigned short* __restrict__ vt,
    unsigned short* __restrict__ ctx) {
  __shared__ unsigned short ldsK[2][32 * 512];  // 64 KB, chunk-swizzled rows
  __shared__ unsigned short ldsV[2][32 * 512];  // 64 KB, bank-swizzled slots
  __shared__ unsigned short ldsP[128 * 40];     // 10 KB, pad-40 rows
  __shared__ float ldsL[128];                   // per-row l (final)

  const int tid = threadIdx.x;
  const int lane = tid & 63;
  const int wave = tid >> 6;  // 0..7
  const int quad = lane >> 4;
  const int l15 = lane & 15;
  const int b = blockIdx.x >> 3;  // group-local batch 0..3
  const int h = blockIdx.x & 7;
  const int qblk = blockIdx.y << 7;  // 128-row block base within batch
  const float cs = 0.044194173824159216f * 1.4426950408889634f;  // scale*log2e

  // Q fragments for this wave's 16 S-rows (qblk + wave*16 + l15)
  bf16x8 qf[16];
  {
    const unsigned short* qp =
        qk + (long)(b * 1024 + qblk + wave * 16 + l15) * 8192 + h * 512 +
        (quad << 3);
#pragma unroll
    for (int ks = 0; ks < 16; ++ks) qf[ks] = *(const bf16x8*)(qp + ks * 32);
  }

  floatx4 o[32];  // o[qb*4+db]: rows qb*16+quad*4+reg, cols wave*64+db*16+l15
#pragma unroll
  for (int i = 0; i < 32; ++i) o[i] = floatx4{0.f, 0.f, 0.f, 0.f};
  floatx4 l_i = floatx4{0.f, 0.f, 0.f, 0.f};  // per-lane partial row sums

  // V staging source mapping (lane -> slot lane): d-local = lane>>2,
  // kc = ((lane&3) - (lane>>3)) & 3  (inverse of the read swizzle)
  const int st_d = lane >> 2;
  const int st_kc = ((lane & 3) - (lane >> 3)) & 3;

  // prologue: stage K[0] and V[0]
  {
#pragma unroll
    for (int i = 0; i < 4; ++i) {
      int r = i * 8 + wave;
      int gc = (lane & ~15) | ((lane ^ r) & 15);
      GLD16(qk + (long)(b * 1024 + r) * 8192 + 4096 + h * 512 + gc * 8,
            ldsK[0] + r * 512);
    }
#pragma unroll
    for (int i = 0; i < 4; ++i) {
      int j = i * 8 + wave;
      GLD16(vt + (long)(b * 4096 + h * 512 + j * 16 + st_d) * 1024 + st_kc * 8,
            ldsV[0] + j * 512);
    }
  }
  __syncthreads();  // drains K[0]+V[0] DMA

  for (int kt = 0; kt < 32; ++kt) {
    const unsigned short* kb = ldsK[kt & 1];
    const unsigned short* vb = ldsV[kt & 1];
    // prefetch K[kt+1] and V[kt+1]; drained at this iteration's END barrier
    if (kt + 1 < 32) {
#pragma unroll
      for (int i = 0; i < 4; ++i) {
        int r = i * 8 + wave;
        int gc = (lane & ~15) | ((lane ^ r) & 15);
        GLD16(qk + (long)(b * 1024 + (kt + 1) * 32 + r) * 8192 + 4096 +
                  h * 512 + gc * 8,
              ldsK[(kt + 1) & 1] + r * 512);
      }
#pragma unroll
      for (int i = 0; i < 4; ++i) {
        int j = i * 8 + wave;
        GLD16(vt + (long)(b * 4096 + h * 512 + j * 16 + st_d) * 1024 +
                  (kt + 1) * 32 + st_kc * 8,
              ldsV[(kt + 1) & 1] + j * 512);
      }
    }

    // --- S = Q K^T : this wave's 16 rows x 32 keys (reads kb) ---
    floatx4 s0 = floatx4{0.f, 0.f, 0.f, 0.f}, s1 = floatx4{0.f, 0.f, 0.f, 0.f};
#pragma unroll
    for (int ks = 0; ks < 16; ++ks) {
      int ch = ks * 4 + quad;
      int sw = (ch & ~15) | ((ch ^ l15) & 15);
      bf16x8 k0 = *(const bf16x8*)(kb + l15 * 512 + sw * 8);
      bf16x8 k1 = *(const bf16x8*)(kb + (16 + l15) * 512 + sw * 8);
      s0 = __builtin_amdgcn_mfma_f32_16x16x32_bf16(qf[ks], k0, s0, 0, 0, 0);
      s1 = __builtin_amdgcn_mfma_f32_16x16x32_bf16(qf[ks], k1, s1, 0, 0, 0);
    }

    // --- no-max softmax: p = 2^(s*scale*log2e); accumulate per-lane l ---
    {
      unsigned short* pw = ldsP + wave * 16 * 40;
      const int rb = quad << 2;
#pragma unroll
      for (int r = 0; r < 4; ++r) {
        float e0 = __builtin_amdgcn_exp2f(s0[r] * cs);
        float e1 = __builtin_amdgcn_exp2f(s1[r] * cs);
        l_i[r] += e0 + e1;
        pw[(rb + r) * 40 + l15] = f2bf(e0);
        pw[(rb + r) * 40 + 16 + l15] = f2bf(e1);
      }
    }
    // mid-barrier: LDS-only visibility (P); K/V[kt+1] DMAs stay in flight.
    asm volatile("s_waitcnt lgkmcnt(0)\n\ts_barrier" ::: "memory");

    // --- O += P @ V (d-split: this wave's 64 dims) ---
#pragma unroll
    for (int half = 0; half < 2; ++half) {
      bf16x8 pf[4];
#pragma unroll
      for (int q4 = 0; q4 < 4; ++q4)
        pf[q4] = *(const bf16x8*)(ldsP + ((half * 4 + q4) * 16 + l15) * 40 +
                                  (quad << 3));
#pragma unroll
      for (int db = 0; db < 4; ++db) {
        int n = wave * 4 + db;
        bf16x8 vf = *(const bf16x8*)(
            vb + n * 512 + (l15 * 4 + ((quad + (l15 >> 1)) & 3)) * 8);
#pragma unroll
        for (int q4 = 0; q4 < 4; ++q4)
          o[(half * 4 + q4) * 4 + db] = __builtin_amdgcn_mfma_f32_16x16x32_bf16(
              pf[q4], vf, o[(half * 4 + q4) * 4 + db], 0, 0, 0);
      }
    }
    __syncthreads();  // drains K/V[kt+1] DMA; all LDS reads of kt done
  }

  // final l reduction across the 16 lanes holding each row's partials
#pragma unroll
  for (int r = 0; r < 4; ++r) {
    float rs = l_i[r];
    rs += __shfl_xor(rs, 1);
    rs += __shfl_xor(rs, 2);
    rs += __shfl_xor(rs, 4);
    rs += __shfl_xor(rs, 8);
    if (l15 == 0) ldsL[wave * 16 + (quad << 2) + r] = rs;
  }
  __syncthreads();

#pragma unroll
  for (int qb = 0; qb < 8; ++qb) {
    floatx4 lv = *(const floatx4*)(ldsL + qb * 16 + (quad << 2));
    floatx4 inv;
#pragma unroll
    for (int r = 0; r < 4; ++r) inv[r] = 1.0f / lv[r];
#pragma unroll
    for (int db = 0; db < 4; ++db) {
#pragma unroll
      for (int r = 0; r < 4; ++r) {
        long row = (long)(b * 1024 + qblk + qb * 16 + (quad << 2) + r);
        ctx[row * 4096 + h * 512 + wave * 64 + db * 16 + l15] =
            f2bf(o[qb * 4 + db][r] * inv[r]);
      }
    }
  }
}

// ---------------------------------------------------------------------------
// Fused split-K reduce + bias + residual + LayerNorm over last dim (512).
// float4-vectorized, 2 rows per 256-thread block.
// ---------------------------------------------------------------------------
template <int NP, bool WB>
__global__ __launch_bounds__(256) void ln_reduce(
    const float* __restrict__ p, long sP, const float* __restrict__ bias,
    const float* __restrict__ resid, const float* __restrict__ gamma,
    const float* __restrict__ beta, float* __restrict__ of,
    unsigned short* __restrict__ ob) {
  const int rloc = threadIdx.x >> 7;              // 0..1: row within block
  const long row = (long)blockIdx.x * 2 + rloc;
  const int t = threadIdx.x & 127;                // 0..127: col/4 within row
  float4 a = ((const float4*)(p + row * 512))[t];
#pragma unroll
  for (int i = 1; i < NP; ++i) {
    const float4 ai = ((const float4*)(p + i * sP + row * 512))[t];
    a.x += ai.x;
    a.y += ai.y;
    a.z += ai.z;
    a.w += ai.w;
  }
  const float4 rv = ((const float4*)(resid + row * 512))[t];
  const float4 bv = ((const float4*)bias)[t];
  const float x0 = a.x + bv.x + rv.x;
  const float x1 = a.y + bv.y + rv.y;
  const float x2 = a.z + bv.z + rv.z;
  const float x3 = a.w + bv.w + rv.w;
  float s = x0 + x1 + x2 + x3;
  float ss = x0 * x0 + x1 * x1 + x2 * x2 + x3 * x3;
#pragma unroll
  for (int d = 1; d < 64; d <<= 1) {
    s += __shfl_xor(s, d);
    ss += __shfl_xor(ss, d);
  }
  __shared__ float ps[2][2], pq[2][2];
  if ((t & 63) == 0) {
    ps[rloc][t >> 6] = s;
    pq[rloc][t >> 6] = ss;
  }
  __syncthreads();
  s = ps[rloc][0] + ps[rloc][1];
  ss = pq[rloc][0] + pq[rloc][1];
  const float mu = s * (1.0f / 512.0f);
  const float rstd = rsqrtf(ss * (1.0f / 512.0f) - mu * mu + 1e-3f);
  const float4 gv = ((const float4*)gamma)[t];
  const float4 be = ((const float4*)beta)[t];
  float4 y;
  y.x = (x0 - mu) * rstd * gv.x + be.x;
  y.y = (x1 - mu) * rstd * gv.y + be.y;
  y.z = (x2 - mu) * rstd * gv.z + be.z;
  y.w = (x3 - mu) * rstd * gv.w + be.w;
  ((float4*)(of + row * 512))[t] = y;
  if (WB) {
    ushort4 o2;
    o2.x = f2bf(y.x);
    o2.y = f2bf(y.y);
    o2.z = f2bf(y.z);
    o2.w = f2bf(y.w);
    ((ushort4*)(ob + row * 512))[t] = o2;
  }
}

// ---------------------------------------------------------------------------
// Single prologue kernel: 6 weight transposes + x cast + bias concat.
// ---------------------------------------------------------------------------
__global__ __launch_bounds__(256) void prep(
    const float* __restrict__ xq, const float* __restrict__ wq,
    const float* __restrict__ wk, const float* __restrict__ wv,
    const float* __restrict__ wo, const float* __restrict__ w1,
    const float* __restrict__ w2, const float* __restrict__ bq,
    const float* __restrict__ bk, unsigned short* __restrict__ xb,
    unsigned short* __restrict__ wqk_t, unsigned short* __restrict__ wv_t,
    unsigned short* __restrict__ wo_t, unsigned short* __restrict__ w1_t,
    unsigned short* __restrict__ w2_t, float* __restrict__ bqk) {
  __shared__ float tile[32][33];
  int bid = blockIdx.x;
  const int tid = threadIdx.x;
  if (bid < 10240) {  // transpose jobs: in [R][C] fp32 -> out [C][R] bf16
    const float* src;
    unsigned short* dst;
    int R, C, ct, rt;
    if (bid < 2048) {
      src = wq; dst = wqk_t; R = 512; C = 4096; ct = bid % 128; rt = bid / 128;
    } else if (bid < 4096) {
      bid -= 2048;
      src = wk; dst = wqk_t + 4096l * 512; R = 512; C = 4096;
      ct = bid % 128; rt = bid / 128;
    } else if (bid < 6144) {
      bid -= 4096;
      src = wv; dst = wv_t; R = 512; C = 4096; ct = bid % 128; rt = bid / 128;
    } else if (bid < 8192) {
      bid -= 6144;
      src = wo; dst = wo_t; R = 4096; C = 512; ct = bid % 16; rt = bid / 16;
    } else if (bid < 9216) {
      bid -= 8192;
      src = w1; dst = w1_t; R = 512; C = 2048; ct = bid % 64; rt = bid / 64;
    } else {
      bid -= 9216;
      src = w2; dst = w2_t; R = 2048; C = 512; ct = bid % 16; rt = bid / 16;
    }
    const int tx = tid & 31, ty = tid >> 5;
    const int c0 = ct * 32, r0 = rt * 32;
#pragma unroll
    for (int i = 0; i < 4; ++i)
      tile[ty + i * 8][tx] = src[(long)(r0 + ty + i * 8) * C + c0 + tx];
    __syncthreads();
#pragma unroll
    for (int i = 0; i < 4; ++i)
      dst[(long)(c0 + ty + i * 8) * R + r0 + tx] = f2bf(tile[tx][ty + i * 8]);
  } else if (bid < 14336) {  // x fp32 -> bf16 cast
    const int i = (bid - 10240) * 1024 + tid * 4;
    const float4 v = *(const float4*)(xq + i);
    ushort4 o;
    o.x = f2bf(v.x);
    o.y = f2bf(v.y);
    o.z = f2bf(v.z);
    o.w = f2bf(v.w);
    *(ushort4*)(xb + i) = o;
  } else {  // bqk = b_q | b_k concat (8192 floats)
    const int j = (bid - 14336) * 1024 + tid * 4;
    const float4 v =
        (j < 4096) ? *(const float4*)(bq + j) : *(const float4*)(bk + j - 4096);
    *(float4*)(bqk + j) = v;
  }
}

extern "C" void kernel_launch(void* const* d_in, const int* in_sizes, int n_in,
                              void* d_out, int out_size, void* d_ws,
                              size_t ws_size, hipStream_t stream) {
  const float* x = (const float*)d_in[0];
  const float* w_q = (const float*)d_in[1];
  const float* b_q = (const float*)d_in[2];
  const float* w_k = (const float*)d_in[3];
  const float* b_k = (const float*)d_in[4];
  const float* w_v = (const float*)d_in[5];
  const float* b_v = (const float*)d_in[6];
  const float* w_o = (const float*)d_in[7];
  const float* b_o = (const float*)d_in[8];
  const float* w1 = (const float*)d_in[9];
  const float* b1 = (const float*)d_in[10];
  const float* w2 = (const float*)d_in[11];
  const float* b2 = (const float*)d_in[12];
  const float* g1 = (const float*)d_in[13];
  const float* be1 = (const float*)d_in[14];
  const float* g2 = (const float*)d_in[15];
  const float* be2 = (const float*)d_in[16];
  float* out = (float*)d_out;

  char* ws = (char*)d_ws;
  size_t off = 0;
  auto alloc = [&](size_t n) {
    char* p = ws + off;
    off += (n + 255) & ~(size_t)255;
    return p;
  };
  // total ~220 MB (ws_size = 256 MiB)
  unsigned short* xb = (unsigned short*)alloc(8192ll * 512 * 2);       // 8 MB
  unsigned short* wqk_t = (unsigned short*)alloc(8192ll * 512 * 2);    // 8 MB
  unsigned short* wv_t = (unsigned short*)alloc(4096ll * 512 * 2);     // 4 MB
  unsigned short* wo_t = (unsigned short*)alloc(512ll * 4096 * 2);     // 4 MB
  unsigned short* w1_t = (unsigned short*)alloc(2048ll * 512 * 2);     // 2 MB
  unsigned short* w2_t = (unsigned short*)alloc(512ll * 2048 * 2);     // 2 MB
  float* bqk = (float*)alloc(8192ll * 4);                              // 32 KB
  unsigned short* qkb = (unsigned short*)alloc(4096ll * 8192 * 2);     // 64 MB (per group)
  unsigned short* vtb = (unsigned short*)alloc(4ll * 4096 * 1024 * 2); // 32 MB (per group)
  unsigned short* ctxf = (unsigned short*)alloc(8192ll * 4096 * 2);    // 64 MB (full)
  float* proj = (float*)alloc(8192ll * 512 * 4);                       // 16 MB
  unsigned short* projb = xb;      // xb dead after group loop
  unsigned short* h1 = qkb;        // qkb dead after o-proj reduce
  float* pOP = (float*)qkb;        // o-proj split-K partials (2x16 MB, qkb dead after attn)
  float* pF2 = (float*)ctxf;       // ffn2 split-K partials (2x16 MB, ctxf dead after o-proj)

  // fused prologue: 6 weight transposes + x cast + bias concat, one launch
  prep<<<14344, 256, 0, stream>>>(x, w_q, w_k, w_v, w_o, w1, w2, b_q, b_k, xb,
                                  wqk_t, wv_t, wo_t, w1_t, w2_t, bqk);

  for (int g = 0; g < 2; ++g) {
    const unsigned short* xg = xb + (long)g * 4096 * 512;
    // fused q|k projection (M=4096, N=8192, K=512) — 256² dbuf, 512 blocks
    gemm_bt2<1, false><<<dim3(32, 16, 1), 512, 0, stream>>>(
        xg, wqk_t, qkb, bqk, 512, 512, 512, 8192, 0, 0);
    // v^T = w_v^T @ x^T (M=4096, N=1024/batch, z=4) — 256² dbuf, 256 blocks
    gemm_bt2<2, false><<<dim3(4, 16, 4), 512, 0, stream>>>(
        wv_t, xg, vtb, b_v, 512, 512, 512, 1024, 1024ll * 512, 4096ll * 1024);
    // attention -> ctxf slice; grid (bh=32, qblk=8) for XCD locality
    attn<<<dim3(32, 8), 512, 0, stream>>>(qkb, vtb, ctxf + (long)g * 4096 * 4096);
  }
  // O projection, split-K 2x2048 -> 512 blocks (2/CU, 32 K-steps each),
  // now double-buffered (single barrier per K-step).
  gemm_bt<0, false, false, false><<<dim3(4, 64, 2), 256, 0, stream>>>(
      ctxf, wo_t, pOP, nullptr, nullptr, 2048, 4096, 4096, 512, 2048, 2048,
      8192ll * 512, 0);
  // reduce + b_o + residual(x) + LN1 -> proj (fp32) + projb (bf16)
  ln_reduce<2, true><<<4096, 256, 0, stream>>>(pOP, 8192ll * 512, b_o, x, g1,
                                               be1, proj, projb);
  // FFN1 (relu, M=8192, N=2048, K=512) — 256² dbuf, 256 blocks
  gemm_bt2<1, true><<<dim3(8, 32, 1), 512, 0, stream>>>(
      projb, w1_t, h1, b1, 512, 512, 512, 2048, 0, 0);
  // FFN2, split-K 2x1024 -> 512 blocks (2/CU, 16 K-steps), double-buffered
  gemm_bt<0, false, false, false><<<dim3(4, 64, 2), 256, 0, stream>>>(
      h1, w2_t, pF2, nullptr, nullptr, 1024, 2048, 2048, 512, 1024, 1024,
      8192ll * 512, 0);
  // reduce + b2 + residual(proj) + LN2 -> out
  ln_reduce<2, false><<<4096, 256, 0, stream>>>(pF2, 8192ll * 512, b2, proj,
                                                g2, be2, out, nullptr);
}